// Round 1
// baseline (12872.884 us; speedup 1.0000x reference)
//
#include <hip/hip_runtime.h>
#include <hip/hip_bf16.h>
#include <math.h>

#define N_NODES 65536
#define N_GRAPH 256
#define P_NODES 256
#define N_EDGES 1048576
#define AF 92
#define BF 41
#define DIM 64
#define HID 128
#define NLAYER 3
#define CE 16
#define TS 4
#define BN_EPS 1e-5f

__device__ __forceinline__ float softplus_f(float x) {
    // jax.nn.softplus = max(x,0) + log1p(exp(-|x|))
    return fmaxf(x, 0.0f) + log1pf(__expf(-fabsf(x)));
}

// acc[j] += sum_k in[k] * W[k*DIM+j]; K % 4 == 0; `in` 16B-aligned rows.
// W/j indexing is wave-uniform -> scalar loads (SMEM pipe), VALU-bound inner loop.
__device__ __forceinline__ void gemm_rows(float* __restrict__ acc,
                                          const float* __restrict__ in,
                                          const float* __restrict__ W, int K) {
    for (int k = 0; k < K; k += 4) {
        float4 a = *(const float4*)(in + k);
        const float* w0 = W + (size_t)k * DIM;
#pragma unroll
        for (int kk = 0; kk < 4; ++kk) {
            float av = (kk == 0) ? a.x : (kk == 1) ? a.y : (kk == 2) ? a.z : a.w;
            const float* w = w0 + kk * DIM;
#pragma unroll
            for (int j = 0; j < DIM; ++j) acc[j] = fmaf(w[j], av, acc[j]);
        }
    }
}

__global__ __launch_bounds__(128) void k_h0(
    const float* __restrict__ x, const float* __restrict__ charge,
    const float* __restrict__ chW, const float* __restrict__ chb,
    const float* __restrict__ atomW, const float* __restrict__ atomb,
    const int* __restrict__ batch, float* __restrict__ h)
{
    const int n = blockIdx.x * 128 + threadIdx.x;
    float acc[DIM];
#pragma unroll
    for (int j = 0; j < DIM; ++j) acc[j] = atomb[j];
    const float* xr = x + (size_t)n * AF;
    for (int k2 = 0; k2 < AF; k2 += 2) {          // rows are 8B-aligned
        float2 a = *(const float2*)(xr + k2);
        {
            const float* w = atomW + (size_t)k2 * DIM;
#pragma unroll
            for (int j = 0; j < DIM; ++j) acc[j] = fmaf(w[j], a.x, acc[j]);
        }
        {
            const float* w = atomW + (size_t)(k2 + 1) * DIM;
#pragma unroll
            for (int j = 0; j < DIM; ++j) acc[j] = fmaf(w[j], a.y, acc[j]);
        }
    }
    const float cg = charge[batch[n]];
#pragma unroll
    for (int k = 0; k < CE; ++k) {
        float av = fmaf(cg, chW[k], chb[k]);      // charge_feat on the fly
        const float* w = atomW + (size_t)(AF + k) * DIM;
#pragma unroll
        for (int j = 0; j < DIM; ++j) acc[j] = fmaf(w[j], av, acc[j]);
    }
    float* hp = h + (size_t)n * DIM;
#pragma unroll
    for (int j = 0; j < DIM; j += 4)
        *(float4*)(hp + j) = make_float4(acc[j], acc[j+1], acc[j+2], acc[j+3]);
}

__global__ __launch_bounds__(128) void k_e0(
    const float* __restrict__ eattr, const float* __restrict__ bondW,
    const float* __restrict__ bondb, float* __restrict__ e)
{
    const int t = blockIdx.x * 128 + threadIdx.x;
    float acc[DIM];
#pragma unroll
    for (int j = 0; j < DIM; ++j) acc[j] = bondb[j];
    const float* ar = eattr + (size_t)t * BF;
    for (int k = 0; k < BF; ++k) {
        float av = ar[k];
        const float* w = bondW + (size_t)k * DIM;
#pragma unroll
        for (int j = 0; j < DIM; ++j) acc[j] = fmaf(w[j], av, acc[j]);
    }
    float* epp = e + (size_t)t * DIM;
#pragma unroll
    for (int j = 0; j < DIM; j += 4)
        *(float4*)(epp + j) = make_float4(acc[j], acc[j+1], acc[j+2], acc[j+3]);
}

// Fused per-layer edge update + message + scatter.
// xch[k][tid]: per-thread private LDS column (bank = tid%32, 2-way alias = free)
// so GEMM k-loops over intermediates can stay dynamic (no register-array
// dynamic indexing, no giant unroll).
__global__ __launch_bounds__(128) void k_edge(
    const float* __restrict__ h, float* __restrict__ e,
    const int* __restrict__ erow, const int* __restrict__ ecol,
    const float* __restrict__ euW1, const float* __restrict__ eub1,
    const float* __restrict__ euW2, const float* __restrict__ eub2,
    const float* __restrict__ nuW1, const float* __restrict__ nub1,
    const float* __restrict__ nuW2, const float* __restrict__ nub2,
    float* __restrict__ hn)
{
    __shared__ float xch[DIM][128];
    const int t = blockIdx.x * 128 + threadIdx.x;
    const int r = erow[t];
    const int c = ecol[t];
    const float* hs = h + (size_t)r * DIM;
    const float* hd = h + (size_t)c * DIM;
    float* ep = e + (size_t)t * DIM;

    float acc[DIM], acc2[DIM];

    // ---- GEMM1: t1 = [hs|hd|e] @ euW1 + eub1  (K=192)
#pragma unroll
    for (int j = 0; j < DIM; ++j) acc[j] = eub1[j];
    gemm_rows(acc, hs, euW1, DIM);
    gemm_rows(acc, hd, euW1 + 64 * DIM, DIM);
    gemm_rows(acc, ep, euW1 + 128 * DIM, DIM);
#pragma unroll
    for (int j = 0; j < DIM; ++j) xch[j][threadIdx.x] = softplus_f(acc[j]);

    // ---- GEMM2: e_new = sp(t1) @ euW2 + eub2  (K=64)
#pragma unroll
    for (int j = 0; j < DIM; ++j) acc2[j] = eub2[j];
    for (int k = 0; k < DIM; ++k) {
        float av = xch[k][threadIdx.x];
        const float* w = euW2 + (size_t)k * DIM;
#pragma unroll
        for (int j = 0; j < DIM; ++j) acc2[j] = fmaf(w[j], av, acc2[j]);
    }
#pragma unroll
    for (int j = 0; j < DIM; j += 4)
        *(float4*)(ep + j) = make_float4(acc2[j], acc2[j+1], acc2[j+2], acc2[j+3]);
#pragma unroll
    for (int j = 0; j < DIM; ++j) xch[j][threadIdx.x] = acc2[j];

    // ---- GEMM3: t2 = [hs|e_new] @ nuW1 + nub1  (K=128)
#pragma unroll
    for (int j = 0; j < DIM; ++j) acc[j] = nub1[j];
    gemm_rows(acc, hs, nuW1, DIM);
    for (int k = 0; k < DIM; ++k) {
        float av = xch[k][threadIdx.x];
        const float* w = nuW1 + (size_t)(64 + k) * DIM;
#pragma unroll
        for (int j = 0; j < DIM; ++j) acc[j] = fmaf(w[j], av, acc[j]);
    }
#pragma unroll
    for (int j = 0; j < DIM; ++j) xch[j][threadIdx.x] = softplus_f(acc[j]);

    // ---- GEMM4: m = sp(t2) @ nuW2 + nub2  (K=64)
#pragma unroll
    for (int j = 0; j < DIM; ++j) acc2[j] = nub2[j];
    for (int k = 0; k < DIM; ++k) {
        float av = xch[k][threadIdx.x];
        const float* w = nuW2 + (size_t)k * DIM;
#pragma unroll
        for (int j = 0; j < DIM; ++j) acc2[j] = fmaf(w[j], av, acc2[j]);
    }

    // ---- scatter: hn[col] += m  (device-scope fp32 atomics)
    float* hnp = hn + (size_t)c * DIM;
#pragma unroll
    for (int j = 0; j < DIM; ++j) atomicAdd(hnp + j, acc2[j]);
}

__global__ __launch_bounds__(256) void k_bnstats(const float* __restrict__ hn,
                                                 float* __restrict__ stats)
{
    const int j = threadIdx.x & 63;
    const int sub = threadIdx.x >> 6;   // 0..3
    const int r0 = blockIdx.x * 256;
    float s = 0.f, q = 0.f;
    for (int i = 0; i < 64; ++i) {
        float v = hn[(size_t)(r0 + i * 4 + sub) * DIM + j];
        s += v;
        q = fmaf(v, v, q);
    }
    __shared__ float ls[256], lq[256];
    ls[threadIdx.x] = s; lq[threadIdx.x] = q;
    __syncthreads();
    if (threadIdx.x < 128) {
        ls[threadIdx.x] += ls[threadIdx.x + 128];
        lq[threadIdx.x] += lq[threadIdx.x + 128];
    }
    __syncthreads();
    if (threadIdx.x < 64) {
        atomicAdd(&stats[j],      ls[threadIdx.x] + ls[threadIdx.x + 64]);
        atomicAdd(&stats[64 + j], lq[threadIdx.x] + lq[threadIdx.x + 64]);
    }
}

__global__ __launch_bounds__(256) void k_hupd(
    const float* __restrict__ hn, float* __restrict__ h,
    const float* __restrict__ stats, const float* __restrict__ gamma,
    const float* __restrict__ beta)
{
    const size_t idx = (size_t)blockIdx.x * 256 + threadIdx.x;
    const int j = (int)(idx & 63);
    const float inv_n = 1.0f / (float)N_NODES;
    float mu  = stats[j] * inv_n;
    float var = stats[64 + j] * inv_n - mu * mu;   // biased, as reference
    float sc  = gamma[j] * rsqrtf(var + BN_EPS);
    float v   = (hn[idx] - mu) * sc + beta[j];
    h[idx] += softplus_f(v);
}

__global__ __launch_bounds__(64) void k_pool(const float* __restrict__ h,
                                             const int* __restrict__ tsi,
                                             float* __restrict__ gr)
{
    // batch = arange(N)//256 -> counts=256, starts=g*256; tsi in [0,256) -> all valid, nsel=4
    const int g = blockIdx.x, j = threadIdx.x;
    float s = 0.f;
#pragma unroll
    for (int t = 0; t < TS; ++t) {
        int p = tsi[g * TS + t];
        s += h[(size_t)(g * P_NODES + p) * DIM + j];
    }
    gr[g * DIM + j] = s * (1.0f / TS);
}

__global__ __launch_bounds__(128) void k_pred(const float* __restrict__ gr,
    const float* __restrict__ W1, const float* __restrict__ b1,
    const float* __restrict__ W2, const float* __restrict__ b2,
    const float* __restrict__ W3, const float* __restrict__ b3,
    float* __restrict__ out)
{
    const int g = blockIdx.x, j = threadIdx.x;
    __shared__ float zin[DIM], z1[HID], red[HID];
    if (j < DIM) zin[j] = gr[g * DIM + j];
    __syncthreads();
    float a = b1[j];
    for (int k = 0; k < DIM; ++k) a = fmaf(zin[k], W1[k * HID + j], a);
    z1[j] = softplus_f(a);
    __syncthreads();
    float a2 = b2[j];
    for (int k = 0; k < HID; ++k) a2 = fmaf(z1[k], W2[k * HID + j], a2);
    red[j] = softplus_f(a2) * W3[j];   // pred_W3 is [H,1]
    __syncthreads();
    for (int s = 64; s > 0; s >>= 1) {
        if (j < s) red[j] += red[j + s];
        __syncthreads();
    }
    if (j == 0) out[g] = red[0] + b3[0];
}

extern "C" void kernel_launch(void* const* d_in, const int* in_sizes, int n_in,
                              void* d_out, int out_size, void* d_ws, size_t ws_size,
                              hipStream_t stream)
{
    const float* x      = (const float*)d_in[0];
    const float* eattr  = (const float*)d_in[1];
    const float* charge = (const float*)d_in[2];
    const float* chW    = (const float*)d_in[3];
    const float* chb    = (const float*)d_in[4];
    const float* atomW  = (const float*)d_in[5];
    const float* atomb  = (const float*)d_in[6];
    const float* bondW  = (const float*)d_in[7];
    const float* bondb  = (const float*)d_in[8];
    const float* nuW1   = (const float*)d_in[9];
    const float* nub1   = (const float*)d_in[10];
    const float* nuW2   = (const float*)d_in[11];
    const float* nub2   = (const float*)d_in[12];
    const float* euW1   = (const float*)d_in[13];
    const float* eub1   = (const float*)d_in[14];
    const float* euW2   = (const float*)d_in[15];
    const float* eub2   = (const float*)d_in[16];
    const float* gamma  = (const float*)d_in[17];
    const float* beta   = (const float*)d_in[18];
    const float* pW1    = (const float*)d_in[19];
    const float* pb1    = (const float*)d_in[20];
    const float* pW2    = (const float*)d_in[21];
    const float* pb2    = (const float*)d_in[22];
    const float* pW3    = (const float*)d_in[23];
    const float* pb3    = (const float*)d_in[24];
    const int*   eidx   = (const int*)d_in[25];
    const int*   batch  = (const int*)d_in[26];
    const int*   tsi    = (const int*)d_in[27];
    const int* erow = eidx;
    const int* ecol = eidx + N_EDGES;

    // workspace layout: h 16MB | hn 16MB | stats+gr | e 256MB  (≈290MB total)
    char* ws = (char*)d_ws;
    float* h     = (float*)(ws);
    float* hn    = (float*)(ws + ((size_t)16 << 20));
    float* stats = (float*)(ws + ((size_t)32 << 20));
    float* gr    = (float*)(ws + ((size_t)32 << 20) + 8192);
    float* e     = (float*)(ws + ((size_t)34 << 20));

    k_h0<<<N_NODES / 128, 128, 0, stream>>>(x, charge, chW, chb, atomW, atomb, batch, h);
    k_e0<<<N_EDGES / 128, 128, 0, stream>>>(eattr, bondW, bondb, e);

    for (int i = 0; i < NLAYER; ++i) {
        hipMemsetAsync(hn, 0, (size_t)N_NODES * DIM * sizeof(float), stream);
        hipMemsetAsync(stats, 0, 128 * sizeof(float), stream);
        k_edge<<<N_EDGES / 128, 128, 0, stream>>>(h, e, erow, ecol,
            euW1 + (size_t)i * 192 * DIM, eub1 + i * DIM,
            euW2 + (size_t)i * DIM * DIM, eub2 + i * DIM,
            nuW1 + (size_t)i * 128 * DIM, nub1 + i * DIM,
            nuW2 + (size_t)i * DIM * DIM, nub2 + i * DIM,
            hn);
        k_bnstats<<<N_NODES / 256, 256, 0, stream>>>(hn, stats);
        k_hupd<<<(N_NODES * DIM) / 256, 256, 0, stream>>>(hn, h, stats,
            gamma + i * DIM, beta + i * DIM);
    }

    k_pool<<<N_GRAPH, 64, 0, stream>>>(h, tsi, gr);
    k_pred<<<N_GRAPH, HID, 0, stream>>>(gr, pW1, pb1, pW2, pb2, pW3, pb3, (float*)d_out);
}

// Round 2
// 4302.102 us; speedup vs baseline: 2.9922x; 2.9922x over previous
//
#include <hip/hip_runtime.h>
#include <hip/hip_bf16.h>
#include <hip/hip_fp16.h>
#include <math.h>

#define N_NODES 65536
#define N_GRAPH 256
#define P_NODES 256
#define N_EDGES 1048576
#define AF 92
#define BF 41
#define DIM 64
#define HID 128
#define NLAYER 3
#define CE 16
#define TS 4
#define BN_EPS 1e-5f

__device__ __forceinline__ float softplus_f(float x) {
    return fmaxf(x, 0.0f) + log1pf(__expf(-fabsf(x)));
}

// ---------------------------------------------------------------- initial h
__global__ __launch_bounds__(128) void k_h0(
    const float* __restrict__ x, const float* __restrict__ charge,
    const float* __restrict__ chW, const float* __restrict__ chb,
    const float* __restrict__ atomW, const float* __restrict__ atomb,
    const int* __restrict__ batch, float* __restrict__ h)
{
    const int n = blockIdx.x * 128 + threadIdx.x;
    float acc[DIM];
#pragma unroll
    for (int j = 0; j < DIM; ++j) acc[j] = atomb[j];
    const float* xr = x + (size_t)n * AF;
    for (int k2 = 0; k2 < AF; k2 += 2) {
        float2 a = *(const float2*)(xr + k2);
        {
            const float* w = atomW + (size_t)k2 * DIM;
#pragma unroll
            for (int j = 0; j < DIM; ++j) acc[j] = fmaf(w[j], a.x, acc[j]);
        }
        {
            const float* w = atomW + (size_t)(k2 + 1) * DIM;
#pragma unroll
            for (int j = 0; j < DIM; ++j) acc[j] = fmaf(w[j], a.y, acc[j]);
        }
    }
    const float cg = charge[batch[n]];
#pragma unroll
    for (int k = 0; k < CE; ++k) {
        float av = fmaf(cg, chW[k], chb[k]);
        const float* w = atomW + (size_t)(AF + k) * DIM;
#pragma unroll
        for (int j = 0; j < DIM; ++j) acc[j] = fmaf(w[j], av, acc[j]);
    }
    float* hp = h + (size_t)n * DIM;
#pragma unroll
    for (int j = 0; j < DIM; j += 4)
        *(float4*)(hp + j) = make_float4(acc[j], acc[j+1], acc[j+2], acc[j+3]);
}

// ------------------------------------------- initial e, stored TRANSPOSED fp16
__global__ __launch_bounds__(128) void k_e0(
    const float* __restrict__ eattr, const float* __restrict__ bondW,
    const float* __restrict__ bondb, __half* __restrict__ eT)
{
    const int t = blockIdx.x * 128 + threadIdx.x;
    float acc[DIM];
#pragma unroll
    for (int j = 0; j < DIM; ++j) acc[j] = bondb[j];
    const float* ar = eattr + (size_t)t * BF;
    for (int k = 0; k < BF; ++k) {
        float av = ar[k];
        const float* w = bondW + (size_t)k * DIM;
#pragma unroll
        for (int j = 0; j < DIM; ++j) acc[j] = fmaf(w[j], av, acc[j]);
    }
#pragma unroll
    for (int j = 0; j < DIM; ++j)
        eT[(size_t)j * N_EDGES + t] = __float2half(acc[j]);
}

// ---------------------------------------------------------------- CSR build
__global__ __launch_bounds__(256) void k_hist(const int* __restrict__ ecol,
                                              int* __restrict__ cnt)
{
    int t = blockIdx.x * 256 + threadIdx.x;
    atomicAdd(&cnt[ecol[t]], 1);
}

__global__ __launch_bounds__(256) void k_scan(const int* __restrict__ cnt,
                                              int* __restrict__ starts)
{
    __shared__ int ps[256];
    const int t = threadIdx.x;
    int s = 0;
    for (int i = 0; i < 256; ++i) s += cnt[t * 256 + i];
    ps[t] = s;
    __syncthreads();
    for (int off = 1; off < 256; off <<= 1) {
        int v = (t >= off) ? ps[t - off] : 0;
        __syncthreads();
        ps[t] += v;
        __syncthreads();
    }
    int run = ps[t] - s;                       // exclusive base for this chunk
    for (int i = 0; i < 256; ++i) {
        starts[t * 256 + i] = run;
        run += cnt[t * 256 + i];
    }
    if (t == 255) starts[N_NODES] = run;       // == E
}

__global__ __launch_bounds__(256) void k_scatter(const int* __restrict__ ecol,
                                                 int* __restrict__ cur,
                                                 int* __restrict__ perm)
{
    int t = blockIdx.x * 256 + threadIdx.x;
    int pos = atomicAdd(&cur[ecol[t]], 1);
    perm[pos] = t;
}

// ------------------------------------------------------- fused edge pipeline
// Block = 256 threads = 4 waves, 64 edges/block. Wave q computes output dims
// [q*16, q*16+16) for all 64 edges (lane = edge slot). Weights are indexed
// wave-uniformly (q via readfirstlane) -> scalar loads on the SMEM pipe.
// xin: input tile transposed [k][edge] (staged hd, then hs; hs kept for GEMM3).
// xch: intermediate tile [j][edge]. Both pitch 64: reads are 2-way bank
// aliased (free); staging writes are 4-way (cheap, ~2% of phase time).
__global__ __launch_bounds__(256, 4) void k_edge2(
    const float* __restrict__ h, __half* __restrict__ eT,
    const int* __restrict__ erow, const int* __restrict__ ecol,
    const float* __restrict__ euW1, const float* __restrict__ eub1,
    const float* __restrict__ euW2, const float* __restrict__ eub2,
    const float* __restrict__ nuW1, const float* __restrict__ nub1,
    const float* __restrict__ nuW2, const float* __restrict__ nub2,
    __half* __restrict__ m)
{
    __shared__ float xin[DIM * 64];
    __shared__ float xch[DIM * 64];
    const int tid  = threadIdx.x;
    const int l    = tid & 63;
    const int q    = __builtin_amdgcn_readfirstlane(tid >> 6);
    const int e0   = blockIdx.x * 64;
    const int edge = e0 + l;
    const int se   = tid >> 2;      // staging: edge slot
    const int sseg = tid & 3;       // staging: 16-float segment

    float acc[16], acc2[16];

    // ---- stage hd (transposed into xin)
    {
        const int r = ecol[e0 + se];
        const float* hp = h + (size_t)r * DIM + sseg * 16;
#pragma unroll
        for (int i = 0; i < 4; ++i) {
            float4 v = *(const float4*)(hp + i * 4);
            int k = sseg * 16 + i * 4;
            xin[(k + 0) * 64 + se] = v.x;
            xin[(k + 1) * 64 + se] = v.y;
            xin[(k + 2) * 64 + se] = v.z;
            xin[(k + 3) * 64 + se] = v.w;
        }
    }
    __syncthreads();

    // ---- GEMM1 hd part (euW1 rows 64..127)
    {
        const float* bb = eub1 + q * 16;
#pragma unroll
        for (int jj = 0; jj < 16; ++jj) acc[jj] = bb[jj];
    }
#pragma unroll 4
    for (int k = 0; k < DIM; ++k) {
        float av = xin[k * 64 + l];
        const float* w = euW1 + (size_t)(64 + k) * DIM + q * 16;
#pragma unroll
        for (int jj = 0; jj < 16; ++jj) acc[jj] = fmaf(w[jj], av, acc[jj]);
    }
    __syncthreads();            // everyone done reading hd

    // ---- stage hs (overwrites xin; stays resident through GEMM3)
    {
        const int r = erow[e0 + se];
        const float* hp = h + (size_t)r * DIM + sseg * 16;
#pragma unroll
        for (int i = 0; i < 4; ++i) {
            float4 v = *(const float4*)(hp + i * 4);
            int k = sseg * 16 + i * 4;
            xin[(k + 0) * 64 + se] = v.x;
            xin[(k + 1) * 64 + se] = v.y;
            xin[(k + 2) * 64 + se] = v.z;
            xin[(k + 3) * 64 + se] = v.w;
        }
    }
    __syncthreads();

    // ---- GEMM1 hs part (rows 0..63)
#pragma unroll 4
    for (int k = 0; k < DIM; ++k) {
        float av = xin[k * 64 + l];
        const float* w = euW1 + (size_t)k * DIM + q * 16;
#pragma unroll
        for (int jj = 0; jj < 16; ++jj) acc[jj] = fmaf(w[jj], av, acc[jj]);
    }
    // ---- GEMM1 e part (rows 128..191), read transposed eT: coalesced
#pragma unroll 4
    for (int k = 0; k < DIM; ++k) {
        float av = __half2float(eT[(size_t)k * N_EDGES + edge]);
        const float* w = euW1 + (size_t)(128 + k) * DIM + q * 16;
#pragma unroll
        for (int jj = 0; jj < 16; ++jj) acc[jj] = fmaf(w[jj], av, acc[jj]);
    }
    // softplus(t1) -> xch
#pragma unroll
    for (int jj = 0; jj < 16; ++jj)
        xch[(q * 16 + jj) * 64 + l] = softplus_f(acc[jj]);
    __syncthreads();

    // ---- GEMM2: e_new = sp(t1) @ euW2 + eub2
    {
        const float* bb = eub2 + q * 16;
#pragma unroll
        for (int jj = 0; jj < 16; ++jj) acc2[jj] = bb[jj];
    }
#pragma unroll 4
    for (int k = 0; k < DIM; ++k) {
        float av = xch[k * 64 + l];
        const float* w = euW2 + (size_t)k * DIM + q * 16;
#pragma unroll
        for (int jj = 0; jj < 16; ++jj) acc2[jj] = fmaf(w[jj], av, acc2[jj]);
    }
    // store e_new transposed (coalesced), fp16
#pragma unroll
    for (int jj = 0; jj < 16; ++jj)
        eT[(size_t)(q * 16 + jj) * N_EDGES + edge] = __float2half(acc2[jj]);
    __syncthreads();            // everyone done reading sp(t1)
#pragma unroll
    for (int jj = 0; jj < 16; ++jj)
        xch[(q * 16 + jj) * 64 + l] = acc2[jj];   // e_new (fp32) for GEMM3
    __syncthreads();

    // ---- GEMM3: t2 = [hs | e_new] @ nuW1 + nub1
    {
        const float* bb = nub1 + q * 16;
#pragma unroll
        for (int jj = 0; jj < 16; ++jj) acc[jj] = bb[jj];
    }
#pragma unroll 4
    for (int k = 0; k < DIM; ++k) {
        float av = xin[k * 64 + l];               // hs
        const float* w = nuW1 + (size_t)k * DIM + q * 16;
#pragma unroll
        for (int jj = 0; jj < 16; ++jj) acc[jj] = fmaf(w[jj], av, acc[jj]);
    }
#pragma unroll 4
    for (int k = 0; k < DIM; ++k) {
        float av = xch[k * 64 + l];               // e_new
        const float* w = nuW1 + (size_t)(64 + k) * DIM + q * 16;
#pragma unroll
        for (int jj = 0; jj < 16; ++jj) acc[jj] = fmaf(w[jj], av, acc[jj]);
    }
    __syncthreads();            // everyone done reading e_new
#pragma unroll
    for (int jj = 0; jj < 16; ++jj)
        xch[(q * 16 + jj) * 64 + l] = softplus_f(acc[jj]);
    __syncthreads();

    // ---- GEMM4: m = sp(t2) @ nuW2 + nub2
    {
        const float* bb = nub2 + q * 16;
#pragma unroll
        for (int jj = 0; jj < 16; ++jj) acc2[jj] = bb[jj];
    }
#pragma unroll 4
    for (int k = 0; k < DIM; ++k) {
        float av = xch[k * 64 + l];
        const float* w = nuW2 + (size_t)k * DIM + q * 16;
#pragma unroll
        for (int jj = 0; jj < 16; ++jj) acc2[jj] = fmaf(w[jj], av, acc2[jj]);
    }
    // store m row-major fp16 (aggregation reads rows coalesced)
    __half* mp = m + (size_t)edge * DIM + q * 16;
#pragma unroll
    for (int jj = 0; jj < 16; jj += 2) {
        __half2 hv;
        hv.x = __float2half(acc2[jj]);
        hv.y = __float2half(acc2[jj + 1]);
        *(__half2*)(mp + jj) = hv;
    }
}

// ------------------------------------------------- CSR aggregation (no atomics)
__global__ __launch_bounds__(256) void k_agg(
    const __half* __restrict__ m, const int* __restrict__ starts,
    const int* __restrict__ perm, float* __restrict__ hn)
{
    const int w = threadIdx.x >> 6;
    const int j = threadIdx.x & 63;
    const int n = blockIdx.x * 4 + w;
    const int s = starts[n], e = starts[n + 1];
    float acc = 0.f;
    for (int i = s; i < e; ++i) {
        int ed = perm[i];
        acc += __half2float(m[(size_t)ed * DIM + j]);
    }
    hn[(size_t)n * DIM + j] = acc;
}

// ---------------------------------------------------------------- BN + update
__global__ __launch_bounds__(256) void k_bnstats(const float* __restrict__ hn,
                                                 float* __restrict__ stats)
{
    const int j = threadIdx.x & 63;
    const int sub = threadIdx.x >> 6;
    const int r0 = blockIdx.x * 256;
    float s = 0.f, qq = 0.f;
    for (int i = 0; i < 64; ++i) {
        float v = hn[(size_t)(r0 + i * 4 + sub) * DIM + j];
        s += v;
        qq = fmaf(v, v, qq);
    }
    __shared__ float ls[256], lq[256];
    ls[threadIdx.x] = s; lq[threadIdx.x] = qq;
    __syncthreads();
    if (threadIdx.x < 128) {
        ls[threadIdx.x] += ls[threadIdx.x + 128];
        lq[threadIdx.x] += lq[threadIdx.x + 128];
    }
    __syncthreads();
    if (threadIdx.x < 64) {
        atomicAdd(&stats[j],      ls[threadIdx.x] + ls[threadIdx.x + 64]);
        atomicAdd(&stats[64 + j], lq[threadIdx.x] + lq[threadIdx.x + 64]);
    }
}

__global__ __launch_bounds__(256) void k_hupd(
    const float* __restrict__ hn, float* __restrict__ h,
    const float* __restrict__ stats, const float* __restrict__ gamma,
    const float* __restrict__ beta)
{
    const size_t idx = (size_t)blockIdx.x * 256 + threadIdx.x;
    const int j = (int)(idx & 63);
    const float inv_n = 1.0f / (float)N_NODES;
    float mu  = stats[j] * inv_n;
    float var = stats[64 + j] * inv_n - mu * mu;
    float sc  = gamma[j] * rsqrtf(var + BN_EPS);
    float v   = (hn[idx] - mu) * sc + beta[j];
    h[idx] += softplus_f(v);
}

// ---------------------------------------------------------------- pool + MLP
__global__ __launch_bounds__(64) void k_pool(const float* __restrict__ h,
                                             const int* __restrict__ tsi,
                                             float* __restrict__ gr)
{
    const int g = blockIdx.x, j = threadIdx.x;
    float s = 0.f;
#pragma unroll
    for (int t = 0; t < TS; ++t) {
        int p = tsi[g * TS + t];
        s += h[(size_t)(g * P_NODES + p) * DIM + j];
    }
    gr[g * DIM + j] = s * (1.0f / TS);
}

__global__ __launch_bounds__(128) void k_pred(const float* __restrict__ gr,
    const float* __restrict__ W1, const float* __restrict__ b1,
    const float* __restrict__ W2, const float* __restrict__ b2,
    const float* __restrict__ W3, const float* __restrict__ b3,
    float* __restrict__ out)
{
    const int g = blockIdx.x, j = threadIdx.x;
    __shared__ float zin[DIM], z1[HID], red[HID];
    if (j < DIM) zin[j] = gr[g * DIM + j];
    __syncthreads();
    float a = b1[j];
    for (int k = 0; k < DIM; ++k) a = fmaf(zin[k], W1[k * HID + j], a);
    z1[j] = softplus_f(a);
    __syncthreads();
    float a2 = b2[j];
    for (int k = 0; k < HID; ++k) a2 = fmaf(z1[k], W2[k * HID + j], a2);
    red[j] = softplus_f(a2) * W3[j];
    __syncthreads();
    for (int s = 64; s > 0; s >>= 1) {
        if (j < s) red[j] += red[j + s];
        __syncthreads();
    }
    if (j == 0) out[g] = red[0] + b3[0];
}

extern "C" void kernel_launch(void* const* d_in, const int* in_sizes, int n_in,
                              void* d_out, int out_size, void* d_ws, size_t ws_size,
                              hipStream_t stream)
{
    const float* x      = (const float*)d_in[0];
    const float* eattr  = (const float*)d_in[1];
    const float* charge = (const float*)d_in[2];
    const float* chW    = (const float*)d_in[3];
    const float* chb    = (const float*)d_in[4];
    const float* atomW  = (const float*)d_in[5];
    const float* atomb  = (const float*)d_in[6];
    const float* bondW  = (const float*)d_in[7];
    const float* bondb  = (const float*)d_in[8];
    const float* nuW1   = (const float*)d_in[9];
    const float* nub1   = (const float*)d_in[10];
    const float* nuW2   = (const float*)d_in[11];
    const float* nub2   = (const float*)d_in[12];
    const float* euW1   = (const float*)d_in[13];
    const float* eub1   = (const float*)d_in[14];
    const float* euW2   = (const float*)d_in[15];
    const float* eub2   = (const float*)d_in[16];
    const float* gamma  = (const float*)d_in[17];
    const float* beta   = (const float*)d_in[18];
    const float* pW1    = (const float*)d_in[19];
    const float* pb1    = (const float*)d_in[20];
    const float* pW2    = (const float*)d_in[21];
    const float* pb2    = (const float*)d_in[22];
    const float* pW3    = (const float*)d_in[23];
    const float* pb3    = (const float*)d_in[24];
    const int*   eidx   = (const int*)d_in[25];
    const int*   batch  = (const int*)d_in[26];
    const int*   tsi    = (const int*)d_in[27];
    const int* erow = eidx;
    const int* ecol = eidx + N_EDGES;

    // workspace layout (~296 MB):
    // h@0 16M | hn@16M 16M | stats@32M 4K | gr@32M+64K 64K | counts@33M 256K
    // starts@33.5M 260K | cur@34M 256K | perm@35M 4M | eT@40M 128M | m@168M 128M
    char* ws = (char*)d_ws;
    float*  h      = (float*)(ws);
    float*  hn     = (float*)(ws + ((size_t)16 << 20));
    float*  stats  = (float*)(ws + ((size_t)32 << 20));
    float*  gr     = (float*)(ws + ((size_t)32 << 20) + (64 << 10));
    int*    counts = (int*)  (ws + ((size_t)33 << 20));
    int*    starts = (int*)  (ws + ((size_t)33 << 20) + (512 << 10));
    int*    cur    = (int*)  (ws + ((size_t)34 << 20));
    int*    perm   = (int*)  (ws + ((size_t)35 << 20));
    __half* eT     = (__half*)(ws + ((size_t)40 << 20));
    __half* m      = (__half*)(ws + ((size_t)168 << 20));

    // ---- CSR build (once per call; reused by all 3 layers)
    hipMemsetAsync(counts, 0, N_NODES * sizeof(int), stream);
    k_hist<<<N_EDGES / 256, 256, 0, stream>>>(ecol, counts);
    k_scan<<<1, 256, 0, stream>>>(counts, starts);
    hipMemcpyAsync(cur, starts, N_NODES * sizeof(int),
                   hipMemcpyDeviceToDevice, stream);
    k_scatter<<<N_EDGES / 256, 256, 0, stream>>>(ecol, cur, perm);

    // ---- embeddings
    k_h0<<<N_NODES / 128, 128, 0, stream>>>(x, charge, chW, chb, atomW, atomb, batch, h);
    k_e0<<<N_EDGES / 128, 128, 0, stream>>>(eattr, bondW, bondb, eT);

    // ---- message-passing layers
    for (int i = 0; i < NLAYER; ++i) {
        hipMemsetAsync(stats, 0, 128 * sizeof(float), stream);
        k_edge2<<<N_EDGES / 64, 256, 0, stream>>>(h, eT, erow, ecol,
            euW1 + (size_t)i * 192 * DIM, eub1 + i * DIM,
            euW2 + (size_t)i * DIM * DIM, eub2 + i * DIM,
            nuW1 + (size_t)i * 128 * DIM, nub1 + i * DIM,
            nuW2 + (size_t)i * DIM * DIM, nub2 + i * DIM,
            m);
        k_agg<<<N_NODES / 4, 256, 0, stream>>>(m, starts, perm, hn);
        k_bnstats<<<N_NODES / 256, 256, 0, stream>>>(hn, stats);
        k_hupd<<<(N_NODES * DIM) / 256, 256, 0, stream>>>(hn, h, stats,
            gamma + i * DIM, beta + i * DIM);
    }

    k_pool<<<N_GRAPH, 64, 0, stream>>>(h, tsi, gr);
    k_pred<<<N_GRAPH, HID, 0, stream>>>(gr, pW1, pb1, pW2, pb2, pW3, pb3, (float*)d_out);
}

// Round 3
// 2331.615 us; speedup vs baseline: 5.5210x; 1.8451x over previous
//
#include <hip/hip_runtime.h>
#include <hip/hip_bf16.h>
#include <hip/hip_fp16.h>
#include <math.h>

#define N_NODES 65536
#define N_GRAPH 256
#define P_NODES 256
#define N_EDGES 1048576
#define AF 92
#define BF 41
#define DIM 64
#define HID 128
#define NLAYER 3
#define CE 16
#define TS 4
#define BN_EPS 1e-5f
#define EPB 128   // edges per block in k_edge3

typedef _Float16 half8 __attribute__((ext_vector_type(8)));
typedef float floatx4 __attribute__((ext_vector_type(4)));

__device__ __forceinline__ float softplus_f(float x) {
    return fmaxf(x, 0.0f) + log1pf(__expf(-fabsf(x)));
}

// ---------------------------------------------------------------- initial h
__global__ __launch_bounds__(128) void k_h0(
    const float* __restrict__ x, const float* __restrict__ charge,
    const float* __restrict__ chW, const float* __restrict__ chb,
    const float* __restrict__ atomW, const float* __restrict__ atomb,
    const int* __restrict__ batch, float* __restrict__ h)
{
    const int n = blockIdx.x * 128 + threadIdx.x;
    float acc[DIM];
#pragma unroll
    for (int j = 0; j < DIM; ++j) acc[j] = atomb[j];
    const float* xr = x + (size_t)n * AF;
    for (int k2 = 0; k2 < AF; k2 += 2) {
        float2 a = *(const float2*)(xr + k2);
        {
            const float* w = atomW + (size_t)k2 * DIM;
#pragma unroll
            for (int j = 0; j < DIM; ++j) acc[j] = fmaf(w[j], a.x, acc[j]);
        }
        {
            const float* w = atomW + (size_t)(k2 + 1) * DIM;
#pragma unroll
            for (int j = 0; j < DIM; ++j) acc[j] = fmaf(w[j], a.y, acc[j]);
        }
    }
    const float cg = charge[batch[n]];
#pragma unroll
    for (int k = 0; k < CE; ++k) {
        float av = fmaf(cg, chW[k], chb[k]);
        const float* w = atomW + (size_t)(AF + k) * DIM;
#pragma unroll
        for (int j = 0; j < DIM; ++j) acc[j] = fmaf(w[j], av, acc[j]);
    }
    float* hp = h + (size_t)n * DIM;
#pragma unroll
    for (int j = 0; j < DIM; j += 4)
        *(float4*)(hp + j) = make_float4(acc[j], acc[j+1], acc[j+2], acc[j+3]);
}

// --------------------------------------- initial e, row-major fp16 [edge][64]
__global__ __launch_bounds__(128) void k_e0(
    const float* __restrict__ eattr, const float* __restrict__ bondW,
    const float* __restrict__ bondb, __half* __restrict__ eT)
{
    const int t = blockIdx.x * 128 + threadIdx.x;
    float acc[DIM];
#pragma unroll
    for (int j = 0; j < DIM; ++j) acc[j] = bondb[j];
    const float* ar = eattr + (size_t)t * BF;
    for (int k = 0; k < BF; ++k) {
        float av = ar[k];
        const float* w = bondW + (size_t)k * DIM;
#pragma unroll
        for (int j = 0; j < DIM; ++j) acc[j] = fmaf(w[j], av, acc[j]);
    }
    _Float16* epp = (_Float16*)(eT + (size_t)t * DIM);
#pragma unroll
    for (int j = 0; j < DIM; j += 8) {
        half8 hv;
#pragma unroll
        for (int u = 0; u < 8; ++u) hv[u] = (_Float16)acc[j + u];
        *(half8*)(epp + j) = hv;
    }
}

// ---------------------------------------------------------------- CSR build
__global__ __launch_bounds__(256) void k_hist(const int* __restrict__ ecol,
                                              int* __restrict__ cnt)
{
    int t = blockIdx.x * 256 + threadIdx.x;
    atomicAdd(&cnt[ecol[t]], 1);
}

__global__ __launch_bounds__(256) void k_scan(const int* __restrict__ cnt,
                                              int* __restrict__ starts)
{
    __shared__ int ps[256];
    const int t = threadIdx.x;
    int s = 0;
    for (int i = 0; i < 256; ++i) s += cnt[t * 256 + i];
    ps[t] = s;
    __syncthreads();
    for (int off = 1; off < 256; off <<= 1) {
        int v = (t >= off) ? ps[t - off] : 0;
        __syncthreads();
        ps[t] += v;
        __syncthreads();
    }
    int run = ps[t] - s;
    for (int i = 0; i < 256; ++i) {
        starts[t * 256 + i] = run;
        run += cnt[t * 256 + i];
    }
    if (t == 255) starts[N_NODES] = run;
}

__global__ __launch_bounds__(256) void k_scatter(const int* __restrict__ ecol,
                                                 int* __restrict__ cur,
                                                 int* __restrict__ perm)
{
    int t = blockIdx.x * 256 + threadIdx.x;
    int pos = atomicAdd(&cur[ecol[t]], 1);
    perm[pos] = t;
}

// --------------------------- weight pre-pack into fp16 B-fragment order
// frag f = kIter*4 + ntile; element (f, lane, j):
//   k = kIter*32 + (lane>>4)*8 + j ; n = ntile*16 + (lane&15)
__global__ __launch_bounds__(256) void k_wprep(const float* __restrict__ W,
                                               __half* __restrict__ out, int K)
{
    int idx = blockIdx.x * 256 + threadIdx.x;
    if (idx >= K * 64) return;
    int j    = idx & 7;
    int lane = (idx >> 3) & 63;
    int f    = idx >> 9;
    int ntile = f & 3;
    int kIter = f >> 2;
    int k = kIter * 32 + ((lane >> 4) & 3) * 8 + j;
    int n = ntile * 16 + (lane & 15);
    out[idx] = __float2half(W[k * 64 + n]);
}

// ---------------------------------------------------------------- MFMA edge
__device__ __forceinline__ void init_acc(floatx4 acc[2][4],
                                         const float* __restrict__ b, int mrow)
{
#pragma unroll
    for (int n = 0; n < 4; ++n) {
        float bv = b[n * 16 + mrow];
        floatx4 f = {bv, bv, bv, bv};
        acc[0][n] = f;
        acc[1][n] = f;
    }
}

// One 64-k panel (2 kIters): A from LDS chunks, B frags from global (L2-hot).
__device__ __forceinline__ void gemm_panel(floatx4 acc[2][4],
                                           const _Float16* __restrict__ P,
                                           const __half* __restrict__ Wf,
                                           int fragBase, int base, int quad,
                                           int mrow, int lane)
{
    const _Float16* Wh = (const _Float16*)Wf;
#pragma unroll
    for (int ki = 0; ki < 2; ++ki) {
        const _Float16* pa = P + (size_t)(((ki * 4 + quad) * EPB + base + mrow) * 8);
        half8 a0 = *(const half8*)pa;
        half8 a1 = *(const half8*)(pa + 16 * 8);
#pragma unroll
        for (int n = 0; n < 4; ++n) {
            half8 b = *(const half8*)(Wh +
                ((size_t)(fragBase + ki * 4 + n) * 64 + lane) * 8);
            acc[0][n] = __builtin_amdgcn_mfma_f32_16x16x32_f16(a0, b, acc[0][n], 0, 0, 0);
            acc[1][n] = __builtin_amdgcn_mfma_f32_16x16x32_f16(a1, b, acc[1][n], 0, 0, 0);
        }
    }
}

// C-layout accumulator -> A-chunk layout in LDS (optionally softplus).
__device__ __forceinline__ void cstore_panel(const floatx4 acc[2][4],
                                             _Float16* __restrict__ P,
                                             int base, int quad, int mrow, bool sp)
{
#pragma unroll
    for (int t = 0; t < 2; ++t)
#pragma unroll
        for (int n = 0; n < 4; ++n)
#pragma unroll
            for (int r = 0; r < 4; ++r) {
                int edge = base + t * 16 + quad * 4 + r;
                int d = n * 16 + mrow;
                float v = acc[t][n][r];
                if (sp) v = softplus_f(v);
                P[((d >> 3) * EPB + edge) * 8 + (d & 7)] = (_Float16)v;
            }
}

// A-chunk panel rows -> global row-major fp16 (coalesced 16B/lane).
__device__ __forceinline__ void rows_to_global(const _Float16* __restrict__ P,
                                               __half* __restrict__ dst,
                                               int e0, int base, int lane)
{
#pragma unroll
    for (int i = 0; i < 4; ++i) {
        int idx = i * 64 + lane;
        int eL = base + (idx >> 3);
        int c  = idx & 7;
        half8 v = *(const half8*)&P[(c * EPB + eL) * 8];
        *(half8*)((_Float16*)dst + (size_t)(e0 + eL) * 64 + c * 8) = v;
    }
}

// gather one h row (fp32) -> fp16 A-chunks
__device__ __forceinline__ void stage_h(const float* __restrict__ hrow,
                                        _Float16* __restrict__ P,
                                        int sEdge, int sSeg)
{
    const float* hp = hrow + sSeg * 32;
#pragma unroll
    for (int i = 0; i < 4; ++i) {
        float4 v0 = *(const float4*)(hp + i * 8);
        float4 v1 = *(const float4*)(hp + i * 8 + 4);
        half8 hv;
        hv[0] = (_Float16)v0.x; hv[1] = (_Float16)v0.y;
        hv[2] = (_Float16)v0.z; hv[3] = (_Float16)v0.w;
        hv[4] = (_Float16)v1.x; hv[5] = (_Float16)v1.y;
        hv[6] = (_Float16)v1.z; hv[7] = (_Float16)v1.w;
        *(half8*)&P[((sSeg * 4 + i) * EPB + sEdge) * 8] = hv;
    }
}

// Block = 128 edges, 4 waves; wave w owns edges [32w,32w+32): 2 M-tiles x 4
// N-tiles of mfma_f32_16x16x32_f16. LDS strictly partitioned by wave's edge
// range. Panels: P0 = hs -> sp(t2); P1 = hd -> e -> sp(t1) -> e_new -> m.
__global__ __launch_bounds__(256, 4) void k_edge3(
    const float* __restrict__ h, __half* __restrict__ eT,
    const __half* __restrict__ Wf,
    const float* __restrict__ eub1, const float* __restrict__ eub2,
    const float* __restrict__ nub1, const float* __restrict__ nub2,
    const int* __restrict__ erow, const int* __restrict__ ecol,
    __half* __restrict__ m)
{
    __shared__ __align__(16) _Float16 P0[8 * EPB * 8];
    __shared__ __align__(16) _Float16 P1[8 * EPB * 8];
    const int tid  = threadIdx.x;
    const int lane = tid & 63;
    const int w    = tid >> 6;
    const int quad = lane >> 4;
    const int mrow = lane & 15;
    const int base = w * 32;
    const int e0   = blockIdx.x * EPB;
    const int sEdge = base + (lane >> 1);
    const int sSeg  = lane & 1;

    floatx4 acc[2][4];

    // stage hs -> P0, hd -> P1
    stage_h(h + (size_t)erow[e0 + sEdge] * DIM, P0, sEdge, sSeg);
    stage_h(h + (size_t)ecol[e0 + sEdge] * DIM, P1, sEdge, sSeg);
    __syncthreads();

    // ---- GEMM1: t1 = [hs|hd|e] @ euW1 + eub1
    init_acc(acc, eub1, mrow);
    gemm_panel(acc, P0, Wf, 0, base, quad, mrow, lane);   // hs   (k 0..63)
    gemm_panel(acc, P1, Wf, 8, base, quad, mrow, lane);   // hd   (k 64..127)
    __syncthreads();
    // stage e -> P1 (overwrite hd)
    {
        const _Float16* ep = (const _Float16*)(eT + (size_t)(e0 + sEdge) * DIM) + sSeg * 32;
#pragma unroll
        for (int i = 0; i < 4; ++i) {
            half8 hv = *(const half8*)(ep + i * 8);
            *(half8*)&P1[((sSeg * 4 + i) * EPB + sEdge) * 8] = hv;
        }
    }
    __syncthreads();
    gemm_panel(acc, P1, Wf, 16, base, quad, mrow, lane);  // e    (k 128..191)
    __syncthreads();
    cstore_panel(acc, P1, base, quad, mrow, true);        // sp(t1) -> P1
    __syncthreads();

    // ---- GEMM2: e_new = sp(t1) @ euW2 + eub2
    init_acc(acc, eub2, mrow);
    gemm_panel(acc, P1, Wf, 24, base, quad, mrow, lane);
    __syncthreads();
    cstore_panel(acc, P1, base, quad, mrow, false);       // e_new -> P1
    __syncthreads();
    rows_to_global(P1, eT, e0, base, lane);               // persist e_new

    // ---- GEMM3: t2 = [hs|e_new] @ nuW1 + nub1
    init_acc(acc, nub1, mrow);
    gemm_panel(acc, P0, Wf, 32, base, quad, mrow, lane);  // hs    (k 0..63)
    gemm_panel(acc, P1, Wf, 40, base, quad, mrow, lane);  // e_new (k 64..127)
    __syncthreads();
    cstore_panel(acc, P0, base, quad, mrow, true);        // sp(t2) -> P0
    __syncthreads();

    // ---- GEMM4: m = sp(t2) @ nuW2 + nub2
    init_acc(acc, nub2, mrow);
    gemm_panel(acc, P0, Wf, 48, base, quad, mrow, lane);
    __syncthreads();
    cstore_panel(acc, P1, base, quad, mrow, false);       // m -> P1
    __syncthreads();
    rows_to_global(P1, m, e0, base, lane);
}

// ------------------------------------------------- CSR aggregation (no atomics)
__global__ __launch_bounds__(256) void k_agg(
    const __half* __restrict__ m, const int* __restrict__ starts,
    const int* __restrict__ perm, float* __restrict__ hn)
{
    const int w = threadIdx.x >> 6;
    const int j = threadIdx.x & 63;
    const int n = blockIdx.x * 4 + w;
    const int s = starts[n], e = starts[n + 1];
    float acc = 0.f;
    for (int i = s; i < e; ++i) {
        int ed = perm[i];
        acc += __half2float(m[(size_t)ed * DIM + j]);
    }
    hn[(size_t)n * DIM + j] = acc;
}

// ---------------------------------------------------------------- BN + update
__global__ __launch_bounds__(256) void k_bnstats(const float* __restrict__ hn,
                                                 float* __restrict__ stats)
{
    const int j = threadIdx.x & 63;
    const int sub = threadIdx.x >> 6;
    const int r0 = blockIdx.x * 256;
    float s = 0.f, qq = 0.f;
    for (int i = 0; i < 64; ++i) {
        float v = hn[(size_t)(r0 + i * 4 + sub) * DIM + j];
        s += v;
        qq = fmaf(v, v, qq);
    }
    __shared__ float ls[256], lq[256];
    ls[threadIdx.x] = s; lq[threadIdx.x] = qq;
    __syncthreads();
    if (threadIdx.x < 128) {
        ls[threadIdx.x] += ls[threadIdx.x + 128];
        lq[threadIdx.x] += lq[threadIdx.x + 128];
    }
    __syncthreads();
    if (threadIdx.x < 64) {
        atomicAdd(&stats[j],      ls[threadIdx.x] + ls[threadIdx.x + 64]);
        atomicAdd(&stats[64 + j], lq[threadIdx.x] + lq[threadIdx.x + 64]);
    }
}

__global__ __launch_bounds__(256) void k_hupd(
    const float* __restrict__ hn, float* __restrict__ h,
    const float* __restrict__ stats, const float* __restrict__ gamma,
    const float* __restrict__ beta)
{
    const size_t idx = (size_t)blockIdx.x * 256 + threadIdx.x;
    const int j = (int)(idx & 63);
    const float inv_n = 1.0f / (float)N_NODES;
    float mu  = stats[j] * inv_n;
    float var = stats[64 + j] * inv_n - mu * mu;
    float sc  = gamma[j] * rsqrtf(var + BN_EPS);
    float v   = (hn[idx] - mu) * sc + beta[j];
    h[idx] += softplus_f(v);
}

// ---------------------------------------------------------------- pool + MLP
__global__ __launch_bounds__(64) void k_pool(const float* __restrict__ h,
                                             const int* __restrict__ tsi,
                                             float* __restrict__ gr)
{
    const int g = blockIdx.x, j = threadIdx.x;
    float s = 0.f;
#pragma unroll
    for (int t = 0; t < TS; ++t) {
        int p = tsi[g * TS + t];
        s += h[(size_t)(g * P_NODES + p) * DIM + j];
    }
    gr[g * DIM + j] = s * (1.0f / TS);
}

__global__ __launch_bounds__(128) void k_pred(const float* __restrict__ gr,
    const float* __restrict__ W1, const float* __restrict__ b1,
    const float* __restrict__ W2, const float* __restrict__ b2,
    const float* __restrict__ W3, const float* __restrict__ b3,
    float* __restrict__ out)
{
    const int g = blockIdx.x, j = threadIdx.x;
    __shared__ float zin[DIM], z1[HID], red[HID];
    if (j < DIM) zin[j] = gr[g * DIM + j];
    __syncthreads();
    float a = b1[j];
    for (int k = 0; k < DIM; ++k) a = fmaf(zin[k], W1[k * HID + j], a);
    z1[j] = softplus_f(a);
    __syncthreads();
    float a2 = b2[j];
    for (int k = 0; k < HID; ++k) a2 = fmaf(z1[k], W2[k * HID + j], a2);
    red[j] = softplus_f(a2) * W3[j];
    __syncthreads();
    for (int s = 64; s > 0; s >>= 1) {
        if (j < s) red[j] += red[j + s];
        __syncthreads();
    }
    if (j == 0) out[g] = red[0] + b3[0];
}

extern "C" void kernel_launch(void* const* d_in, const int* in_sizes, int n_in,
                              void* d_out, int out_size, void* d_ws, size_t ws_size,
                              hipStream_t stream)
{
    const float* x      = (const float*)d_in[0];
    const float* eattr  = (const float*)d_in[1];
    const float* charge = (const float*)d_in[2];
    const float* chW    = (const float*)d_in[3];
    const float* chb    = (const float*)d_in[4];
    const float* atomW  = (const float*)d_in[5];
    const float* atomb  = (const float*)d_in[6];
    const float* bondW  = (const float*)d_in[7];
    const float* bondb  = (const float*)d_in[8];
    const float* nuW1   = (const float*)d_in[9];
    const float* nub1   = (const float*)d_in[10];
    const float* nuW2   = (const float*)d_in[11];
    const float* nub2   = (const float*)d_in[12];
    const float* euW1   = (const float*)d_in[13];
    const float* eub1   = (const float*)d_in[14];
    const float* euW2   = (const float*)d_in[15];
    const float* eub2   = (const float*)d_in[16];
    const float* gamma  = (const float*)d_in[17];
    const float* beta   = (const float*)d_in[18];
    const float* pW1    = (const float*)d_in[19];
    const float* pb1    = (const float*)d_in[20];
    const float* pW2    = (const float*)d_in[21];
    const float* pb2    = (const float*)d_in[22];
    const float* pW3    = (const float*)d_in[23];
    const float* pb3    = (const float*)d_in[24];
    const int*   eidx   = (const int*)d_in[25];
    const int*   batch  = (const int*)d_in[26];
    const int*   tsi    = (const int*)d_in[27];
    const int* erow = eidx;
    const int* ecol = eidx + N_EDGES;

    // workspace (~296 MB):
    // h@0 16M | hn@16M | stats@32M | gr@32M+64K | counts@33M 256K |
    // starts@33M+256K | cur@33M+768K | Wfrag@34M 192K | perm@35M 4M |
    // eT@40M 128M | m@168M 128M
    char* ws = (char*)d_ws;
    float*  h      = (float*)(ws);
    float*  hn     = (float*)(ws + ((size_t)16 << 20));
    float*  stats  = (float*)(ws + ((size_t)32 << 20));
    float*  gr     = (float*)(ws + ((size_t)32 << 20) + (64 << 10));
    int*    counts = (int*)  (ws + ((size_t)33 << 20));
    int*    starts = (int*)  (ws + ((size_t)33 << 20) + (256 << 10));
    int*    cur    = (int*)  (ws + ((size_t)33 << 20) + (768 << 10));
    __half* Wfrag  = (__half*)(ws + ((size_t)34 << 20));
    int*    perm   = (int*)  (ws + ((size_t)35 << 20));
    __half* eT     = (__half*)(ws + ((size_t)40 << 20));
    __half* m      = (__half*)(ws + ((size_t)168 << 20));

    // ---- CSR build (reused by all layers)
    hipMemsetAsync(counts, 0, N_NODES * sizeof(int), stream);
    k_hist<<<N_EDGES / 256, 256, 0, stream>>>(ecol, counts);
    k_scan<<<1, 256, 0, stream>>>(counts, starts);
    hipMemcpyAsync(cur, starts, N_NODES * sizeof(int),
                   hipMemcpyDeviceToDevice, stream);
    k_scatter<<<N_EDGES / 256, 256, 0, stream>>>(ecol, cur, perm);

    // ---- weight fragment pre-pack (fp16), per layer:
    // euW1 frags 0..23 | euW2 24..31 | nuW1 32..47 | nuW2 48..55
    const size_t LW = 28672;  // halves per layer
    for (int i = 0; i < NLAYER; ++i) {
        k_wprep<<<48, 256, 0, stream>>>(euW1 + (size_t)i * 192 * DIM,
                                        Wfrag + i * LW + 0,     192);
        k_wprep<<<16, 256, 0, stream>>>(euW2 + (size_t)i * DIM * DIM,
                                        Wfrag + i * LW + 12288, 64);
        k_wprep<<<32, 256, 0, stream>>>(nuW1 + (size_t)i * 128 * DIM,
                                        Wfrag + i * LW + 16384, 128);
        k_wprep<<<16, 256, 0, stream>>>(nuW2 + (size_t)i * DIM * DIM,
                                        Wfrag + i * LW + 24576, 64);
    }

    // ---- embeddings
    k_h0<<<N_NODES / 128, 128, 0, stream>>>(x, charge, chW, chb, atomW, atomb, batch, h);
    k_e0<<<N_EDGES / 128, 128, 0, stream>>>(eattr, bondW, bondb, eT);

    // ---- message-passing layers
    for (int i = 0; i < NLAYER; ++i) {
        hipMemsetAsync(stats, 0, 128 * sizeof(float), stream);
        k_edge3<<<N_EDGES / EPB, 256, 0, stream>>>(h, eT, Wfrag + i * LW,
            eub1 + i * DIM, eub2 + i * DIM, nub1 + i * DIM, nub2 + i * DIM,
            erow, ecol, m);
        k_agg<<<N_NODES / 4, 256, 0, stream>>>(m, starts, perm, hn);
        k_bnstats<<<N_NODES / 256, 256, 0, stream>>>(hn, stats);
        k_hupd<<<(N_NODES * DIM) / 256, 256, 0, stream>>>(hn, h, stats,
            gamma + i * DIM, beta + i * DIM);
    }

    k_pool<<<N_GRAPH, 64, 0, stream>>>(h, tsi, gr);
    k_pred<<<N_GRAPH, HID, 0, stream>>>(gr, pW1, pb1, pW2, pb2, pW3, pb3, (float*)d_out);
}

// Round 4
// 1601.952 us; speedup vs baseline: 8.0358x; 1.4555x over previous
//
#include <hip/hip_runtime.h>
#include <hip/hip_bf16.h>
#include <hip/hip_fp16.h>
#include <math.h>

#define N_NODES 65536
#define N_GRAPH 256
#define P_NODES 256
#define N_EDGES 1048576
#define AF 92
#define BF 41
#define DIM 64
#define HID 128
#define NLAYER 3
#define CE 16
#define TS 4
#define BN_EPS 1e-5f
#define EPW 32        // edges per block (one wave) in k_edge4
#define PSTRIDE 33    // padded edge-dim stride of LDS panels (conflict fix)

typedef _Float16 half8 __attribute__((ext_vector_type(8)));
typedef float floatx4 __attribute__((ext_vector_type(4)));

// fast softplus: native v_exp/v_log, abs err ~1e-7 (budget 2e-2)
__device__ __forceinline__ float softplus_f(float x) {
    return fmaxf(x, 0.0f) + __logf(1.0f + __expf(-fabsf(x)));
}

// ---------------------------------------------------------------- initial h
__global__ __launch_bounds__(128) void k_h0(
    const float* __restrict__ x, const float* __restrict__ charge,
    const float* __restrict__ chW, const float* __restrict__ chb,
    const float* __restrict__ atomW, const float* __restrict__ atomb,
    const int* __restrict__ batch, float* __restrict__ h)
{
    const int n = blockIdx.x * 128 + threadIdx.x;
    float acc[DIM];
#pragma unroll
    for (int j = 0; j < DIM; ++j) acc[j] = atomb[j];
    const float* xr = x + (size_t)n * AF;
    for (int k2 = 0; k2 < AF; k2 += 2) {
        float2 a = *(const float2*)(xr + k2);
        {
            const float* w = atomW + (size_t)k2 * DIM;
#pragma unroll
            for (int j = 0; j < DIM; ++j) acc[j] = fmaf(w[j], a.x, acc[j]);
        }
        {
            const float* w = atomW + (size_t)(k2 + 1) * DIM;
#pragma unroll
            for (int j = 0; j < DIM; ++j) acc[j] = fmaf(w[j], a.y, acc[j]);
        }
    }
    const float cg = charge[batch[n]];
#pragma unroll
    for (int k = 0; k < CE; ++k) {
        float av = fmaf(cg, chW[k], chb[k]);
        const float* w = atomW + (size_t)(AF + k) * DIM;
#pragma unroll
        for (int j = 0; j < DIM; ++j) acc[j] = fmaf(w[j], av, acc[j]);
    }
    float* hp = h + (size_t)n * DIM;
#pragma unroll
    for (int j = 0; j < DIM; j += 4)
        *(float4*)(hp + j) = make_float4(acc[j], acc[j+1], acc[j+2], acc[j+3]);
}

// ---- initial e in CSR (dst-sorted) order: slot t holds edge perm[t]
__global__ __launch_bounds__(128) void k_e0(
    const float* __restrict__ eattr, const float* __restrict__ bondW,
    const float* __restrict__ bondb, const int* __restrict__ perm,
    __half* __restrict__ eT)
{
    const int t = blockIdx.x * 128 + threadIdx.x;
    float acc[DIM];
#pragma unroll
    for (int j = 0; j < DIM; ++j) acc[j] = bondb[j];
    const float* ar = eattr + (size_t)perm[t] * BF;
    for (int k = 0; k < BF; ++k) {
        float av = ar[k];
        const float* w = bondW + (size_t)k * DIM;
#pragma unroll
        for (int j = 0; j < DIM; ++j) acc[j] = fmaf(w[j], av, acc[j]);
    }
    _Float16* epp = (_Float16*)(eT + (size_t)t * DIM);
#pragma unroll
    for (int j = 0; j < DIM; j += 8) {
        half8 hv;
#pragma unroll
        for (int u = 0; u < 8; ++u) hv[u] = (_Float16)acc[j + u];
        *(half8*)(epp + j) = hv;
    }
}

// ---------------------------------------------------------------- CSR build
__global__ __launch_bounds__(256) void k_hist(const int* __restrict__ ecol,
                                              int* __restrict__ cnt)
{
    int t = blockIdx.x * 256 + threadIdx.x;
    atomicAdd(&cnt[ecol[t]], 1);
}

__global__ __launch_bounds__(256) void k_scan(const int* __restrict__ cnt,
                                              int* __restrict__ starts)
{
    __shared__ int ps[256];
    const int t = threadIdx.x;
    int s = 0;
    for (int i = 0; i < 256; ++i) s += cnt[t * 256 + i];
    ps[t] = s;
    __syncthreads();
    for (int off = 1; off < 256; off <<= 1) {
        int v = (t >= off) ? ps[t - off] : 0;
        __syncthreads();
        ps[t] += v;
        __syncthreads();
    }
    int run = ps[t] - s;
    for (int i = 0; i < 256; ++i) {
        starts[t * 256 + i] = run;
        run += cnt[t * 256 + i];
    }
    if (t == 255) starts[N_NODES] = run;
}

__global__ __launch_bounds__(256) void k_scatter(const int* __restrict__ ecol,
                                                 int* __restrict__ cur,
                                                 int* __restrict__ perm)
{
    int t = blockIdx.x * 256 + threadIdx.x;
    int pos = atomicAdd(&cur[ecol[t]], 1);
    perm[pos] = t;
}

// --------------------------- all weight fragments in one kernel (fp16 B-frag)
// per-layer region: euW1 12288 | euW2 4096 | nuW1 8192 | nuW2 4096 halves
__global__ __launch_bounds__(256) void k_wprep_all(
    const float* __restrict__ euW1, const float* __restrict__ euW2,
    const float* __restrict__ nuW1, const float* __restrict__ nuW2,
    __half* __restrict__ out)
{
    const int idx = blockIdx.x * 256 + threadIdx.x;   // grid = 3*28672 threads
    const int layer = idx / 28672;
    int off = idx - layer * 28672;
    const float* W;
    if (off < 12288)        { W = euW1 + (size_t)layer * 192 * DIM; }
    else if (off < 16384)   { W = euW2 + (size_t)layer * DIM * DIM; off -= 12288; }
    else if (off < 24576)   { W = nuW1 + (size_t)layer * 128 * DIM; off -= 16384; }
    else                    { W = nuW2 + (size_t)layer * DIM * DIM; off -= 24576; }
    int j    = off & 7;
    int lane = (off >> 3) & 63;
    int f    = off >> 9;
    int ntile = f & 3;
    int kIter = f >> 2;
    int k = kIter * 32 + ((lane >> 4) & 3) * 8 + j;
    int n = ntile * 16 + (lane & 15);
    out[idx] = __float2half(W[k * 64 + n]);
}

// ---------------------------------------------------------------- MFMA edge
__device__ __forceinline__ void init_acc(floatx4 acc[2][4],
                                         const float* __restrict__ b, int mrow)
{
#pragma unroll
    for (int n = 0; n < 4; ++n) {
        float bv = b[n * 16 + mrow];
        floatx4 f = {bv, bv, bv, bv};
        acc[0][n] = f;
        acc[1][n] = f;
    }
}

__device__ __forceinline__ void gemm_panel(floatx4 acc[2][4],
                                           const _Float16* __restrict__ P,
                                           const __half* __restrict__ Wf,
                                           int fragBase, int quad,
                                           int mrow, int lane)
{
    const _Float16* Wh = (const _Float16*)Wf;
#pragma unroll
    for (int ki = 0; ki < 2; ++ki) {
        const _Float16* pa = P + (size_t)(((ki * 4 + quad) * PSTRIDE + mrow) * 8);
        half8 a0 = *(const half8*)pa;
        half8 a1 = *(const half8*)(pa + 16 * 8);
#pragma unroll
        for (int n = 0; n < 4; ++n) {
            half8 b = *(const half8*)(Wh +
                ((size_t)(fragBase + ki * 4 + n) * 64 + lane) * 8);
            acc[0][n] = __builtin_amdgcn_mfma_f32_16x16x32_f16(a0, b, acc[0][n], 0, 0, 0);
            acc[1][n] = __builtin_amdgcn_mfma_f32_16x16x32_f16(a1, b, acc[1][n], 0, 0, 0);
        }
    }
}

__device__ __forceinline__ void cstore_panel(const floatx4 acc[2][4],
                                             _Float16* __restrict__ P,
                                             int quad, int mrow, bool sp)
{
#pragma unroll
    for (int t = 0; t < 2; ++t)
#pragma unroll
        for (int n = 0; n < 4; ++n)
#pragma unroll
            for (int r = 0; r < 4; ++r) {
                int edge = t * 16 + quad * 4 + r;
                int d = n * 16 + mrow;
                float v = acc[t][n][r];
                if (sp) v = softplus_f(v);
                P[((d >> 3) * PSTRIDE + edge) * 8 + (d & 7)] = (_Float16)v;
            }
}

__device__ __forceinline__ void rows_to_global(const _Float16* __restrict__ P,
                                               __half* __restrict__ dst,
                                               int e0, int lane)
{
#pragma unroll
    for (int i = 0; i < 4; ++i) {
        int idx = i * 64 + lane;
        int eL = idx >> 3;
        int c  = idx & 7;
        half8 v = *(const half8*)&P[(c * PSTRIDE + eL) * 8];
        *(half8*)((_Float16*)dst + (size_t)(e0 + eL) * 64 + c * 8) = v;
    }
}

__device__ __forceinline__ void stage_h(const float* __restrict__ hrow,
                                        _Float16* __restrict__ P,
                                        int sEdge, int sSeg)
{
    const float* hp = hrow + sSeg * 32;
#pragma unroll
    for (int i = 0; i < 4; ++i) {
        float4 v0 = *(const float4*)(hp + i * 8);
        float4 v1 = *(const float4*)(hp + i * 8 + 4);
        half8 hv;
        hv[0] = (_Float16)v0.x; hv[1] = (_Float16)v0.y;
        hv[2] = (_Float16)v0.z; hv[3] = (_Float16)v0.w;
        hv[4] = (_Float16)v1.x; hv[5] = (_Float16)v1.y;
        hv[6] = (_Float16)v1.z; hv[7] = (_Float16)v1.w;
        *(half8*)&P[((sSeg * 4 + i) * PSTRIDE + sEdge) * 8] = hv;
    }
}

// Single-wave block: 64 threads, 32 edges (2 M-tiles x 4 N-tiles per GEMM).
// Workgroup == wave -> compiler elides s_barrier (no vmcnt(0) drains).
// Edges processed in CSR (dst-sorted) order via perm: hd gather is
// near-streaming, m output lands pre-grouped for the segment sum.
__global__ __launch_bounds__(64) void k_edge4(
    const float* __restrict__ h, __half* __restrict__ eT,
    const __half* __restrict__ Wf,
    const float* __restrict__ eub1, const float* __restrict__ eub2,
    const float* __restrict__ nub1, const float* __restrict__ nub2,
    const int* __restrict__ erow, const int* __restrict__ ecol,
    const int* __restrict__ perm,
    __half* __restrict__ m)
{
    __shared__ __align__(16) _Float16 P0[8 * PSTRIDE * 8];
    __shared__ __align__(16) _Float16 P1[8 * PSTRIDE * 8];
    const int lane = threadIdx.x;
    const int quad = lane >> 4;
    const int mrow = lane & 15;
    const int e0   = blockIdx.x * EPW;
    const int sEdge = lane >> 1;
    const int sSeg  = lane & 1;

    floatx4 acc[2][4];

    const int ed = perm[e0 + sEdge];
    stage_h(h + (size_t)erow[ed] * DIM, P0, sEdge, sSeg);   // hs
    stage_h(h + (size_t)ecol[ed] * DIM, P1, sEdge, sSeg);   // hd
    __syncthreads();

    // ---- GEMM1: t1 = [hs|hd|e] @ euW1 + eub1
    init_acc(acc, eub1, mrow);
    gemm_panel(acc, P0, Wf, 0, quad, mrow, lane);    // hs (k 0..63)
    gemm_panel(acc, P1, Wf, 8, quad, mrow, lane);    // hd (k 64..127)
    __syncthreads();
    {   // stage e -> P1 (overwrite hd)
        const _Float16* ep = (const _Float16*)(eT + (size_t)(e0 + sEdge) * DIM) + sSeg * 32;
#pragma unroll
        for (int i = 0; i < 4; ++i) {
            half8 hv = *(const half8*)(ep + i * 8);
            *(half8*)&P1[((sSeg * 4 + i) * PSTRIDE + sEdge) * 8] = hv;
        }
    }
    __syncthreads();
    gemm_panel(acc, P1, Wf, 16, quad, mrow, lane);   // e (k 128..191)
    __syncthreads();
    cstore_panel(acc, P1, quad, mrow, true);         // sp(t1) -> P1
    __syncthreads();

    // ---- GEMM2: e_new = sp(t1) @ euW2 + eub2
    init_acc(acc, eub2, mrow);
    gemm_panel(acc, P1, Wf, 24, quad, mrow, lane);
    __syncthreads();
    cstore_panel(acc, P1, quad, mrow, false);        // e_new -> P1
    __syncthreads();
    rows_to_global(P1, eT, e0, lane);                // persist e_new

    // ---- GEMM3: t2 = [hs|e_new] @ nuW1 + nub1
    init_acc(acc, nub1, mrow);
    gemm_panel(acc, P0, Wf, 32, quad, mrow, lane);   // hs
    gemm_panel(acc, P1, Wf, 40, quad, mrow, lane);   // e_new
    __syncthreads();
    cstore_panel(acc, P0, quad, mrow, true);         // sp(t2) -> P0
    __syncthreads();

    // ---- GEMM4: m = sp(t2) @ nuW2 + nub2
    init_acc(acc, nub2, mrow);
    gemm_panel(acc, P0, Wf, 48, quad, mrow, lane);
    __syncthreads();
    cstore_panel(acc, P1, quad, mrow, false);        // m -> P1
    __syncthreads();
    rows_to_global(P1, m, e0, lane);
}

// -------------------- segment sum over contiguous (dst-sorted) m rows
__global__ __launch_bounds__(256) void k_agg(
    const __half2* __restrict__ m2, const int* __restrict__ starts,
    float* __restrict__ hn)
{
    const int w = threadIdx.x >> 6;
    const int lane = threadIdx.x & 63;
    const int n = blockIdx.x * 4 + w;
    const int s = starts[n], e = starts[n + 1];
    const int r = lane >> 5, d2 = lane & 31;
    float ax = 0.f, ay = 0.f;
    for (int i = s + r; i < e; i += 2) {
        float2 f = __half22float2(m2[(size_t)i * 32 + d2]);
        ax += f.x; ay += f.y;
    }
    ax += __shfl(ax, lane ^ 32, 64);
    ay += __shfl(ay, lane ^ 32, 64);
    if (r == 0) *(float2*)(hn + (size_t)n * DIM + d2 * 2) = make_float2(ax, ay);
}

// ---------------------------------------------------------------- BN + update
__global__ __launch_bounds__(256) void k_bnstats(const float* __restrict__ hn,
                                                 float* __restrict__ stats)
{
    const int j = threadIdx.x & 63;
    const int sub = threadIdx.x >> 6;
    const int r0 = blockIdx.x * 256;
    float s = 0.f, qq = 0.f;
    for (int i = 0; i < 64; ++i) {
        float v = hn[(size_t)(r0 + i * 4 + sub) * DIM + j];
        s += v;
        qq = fmaf(v, v, qq);
    }
    __shared__ float ls[256], lq[256];
    ls[threadIdx.x] = s; lq[threadIdx.x] = qq;
    __syncthreads();
    if (threadIdx.x < 128) {
        ls[threadIdx.x] += ls[threadIdx.x + 128];
        lq[threadIdx.x] += lq[threadIdx.x + 128];
    }
    __syncthreads();
    if (threadIdx.x < 64) {
        atomicAdd(&stats[j],      ls[threadIdx.x] + ls[threadIdx.x + 64]);
        atomicAdd(&stats[64 + j], lq[threadIdx.x] + lq[threadIdx.x + 64]);
    }
}

__global__ __launch_bounds__(256) void k_hupd(
    const float* __restrict__ hn, float* __restrict__ h,
    const float* __restrict__ stats, const float* __restrict__ gamma,
    const float* __restrict__ beta)
{
    const size_t idx = (size_t)blockIdx.x * 256 + threadIdx.x;
    const int j = (int)(idx & 63);
    const float inv_n = 1.0f / (float)N_NODES;
    float mu  = stats[j] * inv_n;
    float var = stats[64 + j] * inv_n - mu * mu;
    float sc  = gamma[j] * rsqrtf(var + BN_EPS);
    float v   = (hn[idx] - mu) * sc + beta[j];
    h[idx] += softplus_f(v);
}

// ---------------------------------------------------------------- pool + MLP
__global__ __launch_bounds__(64) void k_pool(const float* __restrict__ h,
                                             const int* __restrict__ tsi,
                                             float* __restrict__ gr)
{
    const int g = blockIdx.x, j = threadIdx.x;
    float s = 0.f;
#pragma unroll
    for (int t = 0; t < TS; ++t) {
        int p = tsi[g * TS + t];
        s += h[(size_t)(g * P_NODES + p) * DIM + j];
    }
    gr[g * DIM + j] = s * (1.0f / TS);
}

__global__ __launch_bounds__(128) void k_pred(const float* __restrict__ gr,
    const float* __restrict__ W1, const float* __restrict__ b1,
    const float* __restrict__ W2, const float* __restrict__ b2,
    const float* __restrict__ W3, const float* __restrict__ b3,
    float* __restrict__ out)
{
    const int g = blockIdx.x, j = threadIdx.x;
    __shared__ float zin[DIM], z1[HID], red[HID];
    if (j < DIM) zin[j] = gr[g * DIM + j];
    __syncthreads();
    float a = b1[j];
    for (int k = 0; k < DIM; ++k) a = fmaf(zin[k], W1[k * HID + j], a);
    z1[j] = softplus_f(a);
    __syncthreads();
    float a2 = b2[j];
    for (int k = 0; k < HID; ++k) a2 = fmaf(z1[k], W2[k * HID + j], a2);
    red[j] = softplus_f(a2) * W3[j];
    __syncthreads();
    for (int s = 64; s > 0; s >>= 1) {
        if (j < s) red[j] += red[j + s];
        __syncthreads();
    }
    if (j == 0) out[g] = red[0] + b3[0];
}

extern "C" void kernel_launch(void* const* d_in, const int* in_sizes, int n_in,
                              void* d_out, int out_size, void* d_ws, size_t ws_size,
                              hipStream_t stream)
{
    const float* x      = (const float*)d_in[0];
    const float* eattr  = (const float*)d_in[1];
    const float* charge = (const float*)d_in[2];
    const float* chW    = (const float*)d_in[3];
    const float* chb    = (const float*)d_in[4];
    const float* atomW  = (const float*)d_in[5];
    const float* atomb  = (const float*)d_in[6];
    const float* bondW  = (const float*)d_in[7];
    const float* bondb  = (const float*)d_in[8];
    const float* nuW1   = (const float*)d_in[9];
    const float* nub1   = (const float*)d_in[10];
    const float* nuW2   = (const float*)d_in[11];
    const float* nub2   = (const float*)d_in[12];
    const float* euW1   = (const float*)d_in[13];
    const float* eub1   = (const float*)d_in[14];
    const float* euW2   = (const float*)d_in[15];
    const float* eub2   = (const float*)d_in[16];
    const float* gamma  = (const float*)d_in[17];
    const float* beta   = (const float*)d_in[18];
    const float* pW1    = (const float*)d_in[19];
    const float* pb1    = (const float*)d_in[20];
    const float* pW2    = (const float*)d_in[21];
    const float* pb2    = (const float*)d_in[22];
    const float* pW3    = (const float*)d_in[23];
    const float* pb3    = (const float*)d_in[24];
    const int*   eidx   = (const int*)d_in[25];
    const int*   batch  = (const int*)d_in[26];
    const int*   tsi    = (const int*)d_in[27];
    const int* erow = eidx;
    const int* ecol = eidx + N_EDGES;

    // workspace (~296 MB), same extents as round 3:
    // h@0 16M | hn@16M | stats@32M | gr@32M+64K | counts@33M 256K |
    // starts@33M+256K | cur@33M+768K | Wfrag@34M 192K | perm@35M 4M |
    // eT@40M 128M | m@168M 128M
    char* ws = (char*)d_ws;
    float*  h      = (float*)(ws);
    float*  hn     = (float*)(ws + ((size_t)16 << 20));
    float*  stats  = (float*)(ws + ((size_t)32 << 20));
    float*  gr     = (float*)(ws + ((size_t)32 << 20) + (64 << 10));
    int*    counts = (int*)  (ws + ((size_t)33 << 20));
    int*    starts = (int*)  (ws + ((size_t)33 << 20) + (256 << 10));
    int*    cur    = (int*)  (ws + ((size_t)33 << 20) + (768 << 10));
    __half* Wfrag  = (__half*)(ws + ((size_t)34 << 20));
    int*    perm   = (int*)  (ws + ((size_t)35 << 20));
    __half* eT     = (__half*)(ws + ((size_t)40 << 20));
    __half* m      = (__half*)(ws + ((size_t)168 << 20));

    // ---- CSR build (edge order for ALL layers = dst-sorted via perm)
    hipMemsetAsync(counts, 0, N_NODES * sizeof(int), stream);
    k_hist<<<N_EDGES / 256, 256, 0, stream>>>(ecol, counts);
    k_scan<<<1, 256, 0, stream>>>(counts, starts);
    hipMemcpyAsync(cur, starts, N_NODES * sizeof(int),
                   hipMemcpyDeviceToDevice, stream);
    k_scatter<<<N_EDGES / 256, 256, 0, stream>>>(ecol, cur, perm);

    // ---- weight fragment pre-pack (one kernel, all layers/matrices)
    k_wprep_all<<<(3 * 28672) / 256, 256, 0, stream>>>(euW1, euW2, nuW1, nuW2, Wfrag);

    // ---- embeddings
    k_h0<<<N_NODES / 128, 128, 0, stream>>>(x, charge, chW, chb, atomW, atomb, batch, h);
    k_e0<<<N_EDGES / 128, 128, 0, stream>>>(eattr, bondW, bondb, perm, eT);

    const size_t LW = 28672;
    for (int i = 0; i < NLAYER; ++i) {
        hipMemsetAsync(stats, 0, 128 * sizeof(float), stream);
        k_edge4<<<N_EDGES / EPW, 64, 0, stream>>>(h, eT, Wfrag + i * LW,
            eub1 + i * DIM, eub2 + i * DIM, nub1 + i * DIM, nub2 + i * DIM,
            erow, ecol, perm, m);
        k_agg<<<N_NODES / 4, 256, 0, stream>>>((const __half2*)m, starts, hn);
        k_bnstats<<<N_NODES / 256, 256, 0, stream>>>(hn, stats);
        k_hupd<<<(N_NODES * DIM) / 256, 256, 0, stream>>>(hn, h, stats,
            gamma + i * DIM, beta + i * DIM);
    }

    k_pool<<<N_GRAPH, 64, 0, stream>>>(h, tsi, gr);
    k_pred<<<N_GRAPH, HID, 0, stream>>>(gr, pW1, pb1, pW2, pb2, pW3, pb3, (float*)d_out);
}

// Round 5
// 1505.125 us; speedup vs baseline: 8.5527x; 1.0643x over previous
//
#include <hip/hip_runtime.h>
#include <hip/hip_bf16.h>
#include <hip/hip_fp16.h>
#include <math.h>

#define N_NODES 65536
#define N_GRAPH 256
#define P_NODES 256
#define N_EDGES 1048576
#define AF 92
#define BF 41
#define DIM 64
#define HID 128
#define NLAYER 3
#define CE 16
#define TS 4
#define BN_EPS 1e-5f
#define EPW 32        // edges per block (one wave) in k_edge4
#define PSTRIDE 33    // padded edge-dim stride of LDS panels (conflict fix)

typedef _Float16 half8 __attribute__((ext_vector_type(8)));
typedef float floatx4 __attribute__((ext_vector_type(4)));

// fast softplus: native v_exp/v_log, abs err ~1e-7 (budget 2e-2)
__device__ __forceinline__ float softplus_f(float x) {
    return fmaxf(x, 0.0f) + __logf(1.0f + __expf(-fabsf(x)));
}

// ---------------------------------------------------------------- initial h
// block=64: one block's x-rows = 64*368B = 23KB -> fits 32KB L1 (128 was 47KB)
__global__ __launch_bounds__(64) void k_h0(
    const float* __restrict__ x, const float* __restrict__ charge,
    const float* __restrict__ chW, const float* __restrict__ chb,
    const float* __restrict__ atomW, const float* __restrict__ atomb,
    const int* __restrict__ batch, float* __restrict__ h)
{
    const int n = blockIdx.x * 64 + threadIdx.x;
    float acc[DIM];
#pragma unroll
    for (int j = 0; j < DIM; ++j) acc[j] = atomb[j];
    const float* xr = x + (size_t)n * AF;
    for (int k2 = 0; k2 < AF; k2 += 2) {
        float2 a = *(const float2*)(xr + k2);
        {
            const float* w = atomW + (size_t)k2 * DIM;
#pragma unroll
            for (int j = 0; j < DIM; ++j) acc[j] = fmaf(w[j], a.x, acc[j]);
        }
        {
            const float* w = atomW + (size_t)(k2 + 1) * DIM;
#pragma unroll
            for (int j = 0; j < DIM; ++j) acc[j] = fmaf(w[j], a.y, acc[j]);
        }
    }
    const float cg = charge[batch[n]];
#pragma unroll
    for (int k = 0; k < CE; ++k) {
        float av = fmaf(cg, chW[k], chb[k]);
        const float* w = atomW + (size_t)(AF + k) * DIM;
#pragma unroll
        for (int j = 0; j < DIM; ++j) acc[j] = fmaf(w[j], av, acc[j]);
    }
    float* hp = h + (size_t)n * DIM;
#pragma unroll
    for (int j = 0; j < DIM; j += 4)
        *(float4*)(hp + j) = make_float4(acc[j], acc[j+1], acc[j+2], acc[j+3]);
}

// ---- initial e: NATURAL-order eattr read (L1-reuse, compulsory traffic only),
// scatter-WRITE of the 128B fp16 row to its CSR slot ipos[t] (full-line,
// fire-and-forget — no dependent use, no latency stall).
__global__ __launch_bounds__(128) void k_e0(
    const float* __restrict__ eattr, const float* __restrict__ bondW,
    const float* __restrict__ bondb, const int* __restrict__ ipos,
    __half* __restrict__ eT)
{
    const int t = blockIdx.x * 128 + threadIdx.x;
    float acc[DIM];
#pragma unroll
    for (int j = 0; j < DIM; ++j) acc[j] = bondb[j];
    const float* ar = eattr + (size_t)t * BF;
    for (int k = 0; k < BF; ++k) {
        float av = ar[k];
        const float* w = bondW + (size_t)k * DIM;
#pragma unroll
        for (int j = 0; j < DIM; ++j) acc[j] = fmaf(w[j], av, acc[j]);
    }
    const int slot = ipos[t];
    _Float16* epp = (_Float16*)(eT + (size_t)slot * DIM);
#pragma unroll
    for (int j = 0; j < DIM; j += 8) {
        half8 hv;
#pragma unroll
        for (int u = 0; u < 8; ++u) hv[u] = (_Float16)acc[j + u];
        *(half8*)(epp + j) = hv;
    }
}

// ---------------------------------------------------------------- CSR build
__global__ __launch_bounds__(256) void k_hist(const int* __restrict__ ecol,
                                              int* __restrict__ cnt)
{
    int t = blockIdx.x * 256 + threadIdx.x;
    atomicAdd(&cnt[ecol[t]], 1);
}

__global__ __launch_bounds__(256) void k_scan(const int* __restrict__ cnt,
                                              int* __restrict__ starts)
{
    __shared__ int ps[256];
    const int t = threadIdx.x;
    int s = 0;
    for (int i = 0; i < 256; ++i) s += cnt[t * 256 + i];
    ps[t] = s;
    __syncthreads();
    for (int off = 1; off < 256; off <<= 1) {
        int v = (t >= off) ? ps[t - off] : 0;
        __syncthreads();
        ps[t] += v;
        __syncthreads();
    }
    int run = ps[t] - s;
    for (int i = 0; i < 256; ++i) {
        starts[t * 256 + i] = run;
        run += cnt[t * 256 + i];
    }
    if (t == 255) starts[N_NODES] = run;
}

__global__ __launch_bounds__(256) void k_scatter(const int* __restrict__ ecol,
                                                 int* __restrict__ cur,
                                                 int* __restrict__ perm,
                                                 int* __restrict__ ipos)
{
    int t = blockIdx.x * 256 + threadIdx.x;
    int pos = atomicAdd(&cur[ecol[t]], 1);
    perm[pos] = t;
    ipos[t] = pos;
}

// --------------------------- all weight fragments in one kernel (fp16 B-frag)
// per-layer region: euW1 12288 | euW2 4096 | nuW1 8192 | nuW2 4096 halves
__global__ __launch_bounds__(256) void k_wprep_all(
    const float* __restrict__ euW1, const float* __restrict__ euW2,
    const float* __restrict__ nuW1, const float* __restrict__ nuW2,
    __half* __restrict__ out)
{
    const int idx = blockIdx.x * 256 + threadIdx.x;   // grid = 3*28672 threads
    const int layer = idx / 28672;
    int off = idx - layer * 28672;
    const float* W;
    if (off < 12288)        { W = euW1 + (size_t)layer * 192 * DIM; }
    else if (off < 16384)   { W = euW2 + (size_t)layer * DIM * DIM; off -= 12288; }
    else if (off < 24576)   { W = nuW1 + (size_t)layer * 128 * DIM; off -= 16384; }
    else                    { W = nuW2 + (size_t)layer * DIM * DIM; off -= 24576; }
    int j    = off & 7;
    int lane = (off >> 3) & 63;
    int f    = off >> 9;
    int ntile = f & 3;
    int kIter = f >> 2;
    int k = kIter * 32 + ((lane >> 4) & 3) * 8 + j;
    int n = ntile * 16 + (lane & 15);
    out[idx] = __float2half(W[k * 64 + n]);
}

// ---------------------------------------------------------------- MFMA edge
__device__ __forceinline__ void init_acc(floatx4 acc[2][4],
                                         const float* __restrict__ b, int mrow)
{
#pragma unroll
    for (int n = 0; n < 4; ++n) {
        float bv = b[n * 16 + mrow];
        floatx4 f = {bv, bv, bv, bv};
        acc[0][n] = f;
        acc[1][n] = f;
    }
}

__device__ __forceinline__ void gemm_panel(floatx4 acc[2][4],
                                           const _Float16* __restrict__ P,
                                           const __half* __restrict__ Wf,
                                           int fragBase, int quad,
                                           int mrow, int lane)
{
    const _Float16* Wh = (const _Float16*)Wf;
#pragma unroll
    for (int ki = 0; ki < 2; ++ki) {
        const _Float16* pa = P + (size_t)(((ki * 4 + quad) * PSTRIDE + mrow) * 8);
        half8 a0 = *(const half8*)pa;
        half8 a1 = *(const half8*)(pa + 16 * 8);
#pragma unroll
        for (int n = 0; n < 4; ++n) {
            half8 b = *(const half8*)(Wh +
                ((size_t)(fragBase + ki * 4 + n) * 64 + lane) * 8);
            acc[0][n] = __builtin_amdgcn_mfma_f32_16x16x32_f16(a0, b, acc[0][n], 0, 0, 0);
            acc[1][n] = __builtin_amdgcn_mfma_f32_16x16x32_f16(a1, b, acc[1][n], 0, 0, 0);
        }
    }
}

__device__ __forceinline__ void cstore_panel(const floatx4 acc[2][4],
                                             _Float16* __restrict__ P,
                                             int quad, int mrow, bool sp)
{
#pragma unroll
    for (int t = 0; t < 2; ++t)
#pragma unroll
        for (int n = 0; n < 4; ++n)
#pragma unroll
            for (int r = 0; r < 4; ++r) {
                int edge = t * 16 + quad * 4 + r;
                int d = n * 16 + mrow;
                float v = acc[t][n][r];
                if (sp) v = softplus_f(v);
                P[((d >> 3) * PSTRIDE + edge) * 8 + (d & 7)] = (_Float16)v;
            }
}

__device__ __forceinline__ void rows_to_global(const _Float16* __restrict__ P,
                                               __half* __restrict__ dst,
                                               int e0, int lane)
{
#pragma unroll
    for (int i = 0; i < 4; ++i) {
        int idx = i * 64 + lane;
        int eL = idx >> 3;
        int c  = idx & 7;
        half8 v = *(const half8*)&P[(c * PSTRIDE + eL) * 8];
        *(half8*)((_Float16*)dst + (size_t)(e0 + eL) * 64 + c * 8) = v;
    }
}

__device__ __forceinline__ void stage_h(const float* __restrict__ hrow,
                                        _Float16* __restrict__ P,
                                        int sEdge, int sSeg)
{
    const float* hp = hrow + sSeg * 32;
#pragma unroll
    for (int i = 0; i < 4; ++i) {
        float4 v0 = *(const float4*)(hp + i * 8);
        float4 v1 = *(const float4*)(hp + i * 8 + 4);
        half8 hv;
        hv[0] = (_Float16)v0.x; hv[1] = (_Float16)v0.y;
        hv[2] = (_Float16)v0.z; hv[3] = (_Float16)v0.w;
        hv[4] = (_Float16)v1.x; hv[5] = (_Float16)v1.y;
        hv[6] = (_Float16)v1.z; hv[7] = (_Float16)v1.w;
        *(half8*)&P[((sSeg * 4 + i) * PSTRIDE + sEdge) * 8] = hv;
    }
}

// Single-wave block: 64 threads, 32 edges (2 M-tiles x 4 N-tiles per GEMM).
// Workgroup == wave -> compiler elides s_barrier (no vmcnt(0) drains).
// Edges processed in CSR (dst-sorted) order via perm; eT row prefetched into
// registers at kernel start so the load rides through GEMM1's MFMA latency.
__global__ __launch_bounds__(64) void k_edge4(
    const float* __restrict__ h, __half* __restrict__ eT,
    const __half* __restrict__ Wf,
    const float* __restrict__ eub1, const float* __restrict__ eub2,
    const float* __restrict__ nub1, const float* __restrict__ nub2,
    const int* __restrict__ erow, const int* __restrict__ ecol,
    const int* __restrict__ perm,
    __half* __restrict__ m)
{
    __shared__ __align__(16) _Float16 P0[8 * PSTRIDE * 8];
    __shared__ __align__(16) _Float16 P1[8 * PSTRIDE * 8];
    const int lane = threadIdx.x;
    const int quad = lane >> 4;
    const int mrow = lane & 15;
    const int e0   = blockIdx.x * EPW;
    const int sEdge = lane >> 1;
    const int sSeg  = lane & 1;

    floatx4 acc[2][4];

    // prefetch this wave's e rows (consumed after GEMM1-hd)
    half8 epre[4];
    {
        const _Float16* ep = (const _Float16*)(eT + (size_t)(e0 + sEdge) * DIM) + sSeg * 32;
#pragma unroll
        for (int i = 0; i < 4; ++i) epre[i] = *(const half8*)(ep + i * 8);
    }

    const int ed = perm[e0 + sEdge];
    stage_h(h + (size_t)erow[ed] * DIM, P0, sEdge, sSeg);   // hs
    stage_h(h + (size_t)ecol[ed] * DIM, P1, sEdge, sSeg);   // hd
    __syncthreads();

    // ---- GEMM1: t1 = [hs|hd|e] @ euW1 + eub1
    init_acc(acc, eub1, mrow);
    gemm_panel(acc, P0, Wf, 0, quad, mrow, lane);    // hs (k 0..63)
    gemm_panel(acc, P1, Wf, 8, quad, mrow, lane);    // hd (k 64..127)
    __syncthreads();
    {   // stage prefetched e -> P1 (overwrite hd)
#pragma unroll
        for (int i = 0; i < 4; ++i)
            *(half8*)&P1[((sSeg * 4 + i) * PSTRIDE + sEdge) * 8] = epre[i];
    }
    __syncthreads();
    gemm_panel(acc, P1, Wf, 16, quad, mrow, lane);   // e (k 128..191)
    __syncthreads();
    cstore_panel(acc, P1, quad, mrow, true);         // sp(t1) -> P1
    __syncthreads();

    // ---- GEMM2: e_new = sp(t1) @ euW2 + eub2
    init_acc(acc, eub2, mrow);
    gemm_panel(acc, P1, Wf, 24, quad, mrow, lane);
    __syncthreads();
    cstore_panel(acc, P1, quad, mrow, false);        // e_new -> P1
    __syncthreads();
    rows_to_global(P1, eT, e0, lane);                // persist e_new

    // ---- GEMM3: t2 = [hs|e_new] @ nuW1 + nub1
    init_acc(acc, nub1, mrow);
    gemm_panel(acc, P0, Wf, 32, quad, mrow, lane);   // hs
    gemm_panel(acc, P1, Wf, 40, quad, mrow, lane);   // e_new
    __syncthreads();
    cstore_panel(acc, P0, quad, mrow, true);         // sp(t2) -> P0
    __syncthreads();

    // ---- GEMM4: m = sp(t2) @ nuW2 + nub2
    init_acc(acc, nub2, mrow);
    gemm_panel(acc, P0, Wf, 48, quad, mrow, lane);
    __syncthreads();
    cstore_panel(acc, P1, quad, mrow, false);        // m -> P1
    __syncthreads();
    rows_to_global(P1, m, e0, lane);
}

// -------------------- segment sum over contiguous (dst-sorted) m rows
__global__ __launch_bounds__(256) void k_agg(
    const __half2* __restrict__ m2, const int* __restrict__ starts,
    float* __restrict__ hn)
{
    const int w = threadIdx.x >> 6;
    const int lane = threadIdx.x & 63;
    const int n = blockIdx.x * 4 + w;
    const int s = starts[n], e = starts[n + 1];
    const int r = lane >> 5, d2 = lane & 31;
    float ax = 0.f, ay = 0.f;
    for (int i = s + r; i < e; i += 2) {
        float2 f = __half22float2(m2[(size_t)i * 32 + d2]);
        ax += f.x; ay += f.y;
    }
    ax += __shfl(ax, lane ^ 32, 64);
    ay += __shfl(ay, lane ^ 32, 64);
    if (r == 0) *(float2*)(hn + (size_t)n * DIM + d2 * 2) = make_float2(ax, ay);
}

// ---------------------------------------------------------------- BN + update
__global__ __launch_bounds__(256) void k_bnstats(const float* __restrict__ hn,
                                                 float* __restrict__ stats)
{
    const int j = threadIdx.x & 63;
    const int sub = threadIdx.x >> 6;
    const int r0 = blockIdx.x * 256;
    float s = 0.f, qq = 0.f;
    for (int i = 0; i < 64; ++i) {
        float v = hn[(size_t)(r0 + i * 4 + sub) * DIM + j];
        s += v;
        qq = fmaf(v, v, qq);
    }
    __shared__ float ls[256], lq[256];
    ls[threadIdx.x] = s; lq[threadIdx.x] = qq;
    __syncthreads();
    if (threadIdx.x < 128) {
        ls[threadIdx.x] += ls[threadIdx.x + 128];
        lq[threadIdx.x] += lq[threadIdx.x + 128];
    }
    __syncthreads();
    if (threadIdx.x < 64) {
        atomicAdd(&stats[j],      ls[threadIdx.x] + ls[threadIdx.x + 64]);
        atomicAdd(&stats[64 + j], lq[threadIdx.x] + lq[threadIdx.x + 64]);
    }
}

__global__ __launch_bounds__(256) void k_hupd(
    const float* __restrict__ hn, float* __restrict__ h,
    const float* __restrict__ stats, const float* __restrict__ gamma,
    const float* __restrict__ beta)
{
    const size_t idx = (size_t)blockIdx.x * 256 + threadIdx.x;
    const int j = (int)(idx & 63);
    const float inv_n = 1.0f / (float)N_NODES;
    float mu  = stats[j] * inv_n;
    float var = stats[64 + j] * inv_n - mu * mu;
    float sc  = gamma[j] * rsqrtf(var + BN_EPS);
    float v   = (hn[idx] - mu) * sc + beta[j];
    h[idx] += softplus_f(v);
}

// ---------------------------------------------------------------- pool + MLP
__global__ __launch_bounds__(64) void k_pool(const float* __restrict__ h,
                                             const int* __restrict__ tsi,
                                             float* __restrict__ gr)
{
    const int g = blockIdx.x, j = threadIdx.x;
    float s = 0.f;
#pragma unroll
    for (int t = 0; t < TS; ++t) {
        int p = tsi[g * TS + t];
        s += h[(size_t)(g * P_NODES + p) * DIM + j];
    }
    gr[g * DIM + j] = s * (1.0f / TS);
}

__global__ __launch_bounds__(128) void k_pred(const float* __restrict__ gr,
    const float* __restrict__ W1, const float* __restrict__ b1,
    const float* __restrict__ W2, const float* __restrict__ b2,
    const float* __restrict__ W3, const float* __restrict__ b3,
    float* __restrict__ out)
{
    const int g = blockIdx.x, j = threadIdx.x;
    __shared__ float zin[DIM], z1[HID], red[HID];
    if (j < DIM) zin[j] = gr[g * DIM + j];
    __syncthreads();
    float a = b1[j];
    for (int k = 0; k < DIM; ++k) a = fmaf(zin[k], W1[k * HID + j], a);
    z1[j] = softplus_f(a);
    __syncthreads();
    float a2 = b2[j];
    for (int k = 0; k < HID; ++k) a2 = fmaf(z1[k], W2[k * HID + j], a2);
    red[j] = softplus_f(a2) * W3[j];
    __syncthreads();
    for (int s = 64; s > 0; s >>= 1) {
        if (j < s) red[j] += red[j + s];
        __syncthreads();
    }
    if (j == 0) out[g] = red[0] + b3[0];
}

extern "C" void kernel_launch(void* const* d_in, const int* in_sizes, int n_in,
                              void* d_out, int out_size, void* d_ws, size_t ws_size,
                              hipStream_t stream)
{
    const float* x      = (const float*)d_in[0];
    const float* eattr  = (const float*)d_in[1];
    const float* charge = (const float*)d_in[2];
    const float* chW    = (const float*)d_in[3];
    const float* chb    = (const float*)d_in[4];
    const float* atomW  = (const float*)d_in[5];
    const float* atomb  = (const float*)d_in[6];
    const float* bondW  = (const float*)d_in[7];
    const float* bondb  = (const float*)d_in[8];
    const float* nuW1   = (const float*)d_in[9];
    const float* nub1   = (const float*)d_in[10];
    const float* nuW2   = (const float*)d_in[11];
    const float* nub2   = (const float*)d_in[12];
    const float* euW1   = (const float*)d_in[13];
    const float* eub1   = (const float*)d_in[14];
    const float* euW2   = (const float*)d_in[15];
    const float* eub2   = (const float*)d_in[16];
    const float* gamma  = (const float*)d_in[17];
    const float* beta   = (const float*)d_in[18];
    const float* pW1    = (const float*)d_in[19];
    const float* pb1    = (const float*)d_in[20];
    const float* pW2    = (const float*)d_in[21];
    const float* pb2    = (const float*)d_in[22];
    const float* pW3    = (const float*)d_in[23];
    const float* pb3    = (const float*)d_in[24];
    const int*   eidx   = (const int*)d_in[25];
    const int*   batch  = (const int*)d_in[26];
    const int*   tsi    = (const int*)d_in[27];
    const int* erow = eidx;
    const int* ecol = eidx + N_EDGES;

    // workspace (~296 MB):
    // h@0 16M | hn@16M 16M (ipos aliases first 4M: consumed by k_e0 before
    // k_agg's first write) | stats@32M | gr@32M+64K | counts@33M 256K |
    // starts@33M+256K | cur@33M+768K | Wfrag@34M 192K | perm@35M 4M |
    // eT@40M 128M | m@168M 128M
    char* ws = (char*)d_ws;
    float*  h      = (float*)(ws);
    float*  hn     = (float*)(ws + ((size_t)16 << 20));
    int*    ipos   = (int*)  (ws + ((size_t)16 << 20));   // aliases hn (safe)
    float*  stats  = (float*)(ws + ((size_t)32 << 20));
    float*  gr     = (float*)(ws + ((size_t)32 << 20) + (64 << 10));
    int*    counts = (int*)  (ws + ((size_t)33 << 20));
    int*    starts = (int*)  (ws + ((size_t)33 << 20) + (256 << 10));
    int*    cur    = (int*)  (ws + ((size_t)33 << 20) + (768 << 10));
    __half* Wfrag  = (__half*)(ws + ((size_t)34 << 20));
    int*    perm   = (int*)  (ws + ((size_t)35 << 20));
    __half* eT     = (__half*)(ws + ((size_t)40 << 20));
    __half* m      = (__half*)(ws + ((size_t)168 << 20));

    // ---- CSR build (edge order for ALL layers = dst-sorted via perm/ipos)
    hipMemsetAsync(counts, 0, N_NODES * sizeof(int), stream);
    k_hist<<<N_EDGES / 256, 256, 0, stream>>>(ecol, counts);
    k_scan<<<1, 256, 0, stream>>>(counts, starts);
    hipMemcpyAsync(cur, starts, N_NODES * sizeof(int),
                   hipMemcpyDeviceToDevice, stream);
    k_scatter<<<N_EDGES / 256, 256, 0, stream>>>(ecol, cur, perm, ipos);

    // ---- weight fragment pre-pack (one kernel, all layers/matrices)
    k_wprep_all<<<(3 * 28672) / 256, 256, 0, stream>>>(euW1, euW2, nuW1, nuW2, Wfrag);

    // ---- embeddings
    k_h0<<<N_NODES / 64, 64, 0, stream>>>(x, charge, chW, chb, atomW, atomb, batch, h);
    k_e0<<<N_EDGES / 128, 128, 0, stream>>>(eattr, bondW, bondb, ipos, eT);

    const size_t LW = 28672;
    for (int i = 0; i < NLAYER; ++i) {
        hipMemsetAsync(stats, 0, 128 * sizeof(float), stream);
        k_edge4<<<N_EDGES / EPW, 64, 0, stream>>>(h, eT, Wfrag + i * LW,
            eub1 + i * DIM, eub2 + i * DIM, nub1 + i * DIM, nub2 + i * DIM,
            erow, ecol, perm, m);
        k_agg<<<N_NODES / 4, 256, 0, stream>>>((const __half2*)m, starts, hn);
        k_bnstats<<<N_NODES / 256, 256, 0, stream>>>(hn, stats);
        k_hupd<<<(N_NODES * DIM) / 256, 256, 0, stream>>>(hn, h, stats,
            gamma + i * DIM, beta + i * DIM);
    }

    k_pool<<<N_GRAPH, 64, 0, stream>>>(h, tsi, gr);
    k_pred<<<N_GRAPH, HID, 0, stream>>>(gr, pW1, pb1, pW2, pb2, pW3, pb3, (float*)d_out);
}